// Round 13
// baseline (148.762 us; speedup 1.0000x reference)
//
#include <hip/hip_runtime.h>

// ANCF recommender on MI355X.
// prep (MFMA hidden -> Khid fp8; keys^T -> Vpan fp8 n-panels; colsum partials)
//  -> sreduceA/B (S = colsum, 2-stage tree)
//  -> flash (streaming softmax attention, MX-fp8 mfma_scale 32x32x64 (scales=1.0).
//            Phase = 128 n: two sequential 64-n sub-steps between barriers
//            (same live registers; 2x work per barrier generation). Per wave-
//            phase: 4 QK + 4 PV MFMA, 64 fexp2, 32 pk_add, 32 cvt_pk_fp8,
//            8 permlane32_swap, 16 ds_read_b128, 2 DMA issues.
//            K/V staged via global_load_lds, double-buffered 2x16KB, DMA one
//            full phase ahead; raw s_barrier. 8-wave blocks; grid = 2 blocks/CU.)
//  -> combine (O/l, q2, epilogue (q2+S)W1^T+(q2*S)W2^T, leaky_relu, build og)
//  -> final1/2 (128x128 = og_user^T @ og_item, LDS-tiled, 32-way k-split)
// Workspace required: ~50 MB.

typedef __bf16 bf16x8 __attribute__((ext_vector_type(8)));
typedef float f32x2 __attribute__((ext_vector_type(2)));
typedef float f32x4 __attribute__((ext_vector_type(4)));
typedef float f32x16 __attribute__((ext_vector_type(16)));
typedef unsigned int u32x4 __attribute__((ext_vector_type(4)));
typedef int i32x4 __attribute__((ext_vector_type(4)));
typedef int i32x8 __attribute__((ext_vector_type(8)));

static constexpr int NKEYS  = 100000;
static constexpr int NP     = 102400;          // 32 chunks * 3200 rows
static constexpr int DIM    = 64;
static constexpr int BQ     = 2048;
static constexpr int NCH    = 32;              // grid 32*8*2 = 512 = 2 blocks/CU exactly
static constexpr int CHROWS = NP / NCH;        // 3200
static constexpr int NPH    = CHROWS / 128;    // 25 phases of 128 n
static constexpr int NTIL   = NP / 64;         // 1600
static constexpr float PADCNT = float(NP - NKEYS);   // 2400 pads, each adds fexp2(0) to l
static constexpr float LOG2E  = 1.44269504088896340736f;

#define DEVINL __device__ __forceinline__

DEVINL unsigned int cvtpk(float lo, float hi) {
    unsigned int r;
    asm("v_cvt_pk_bf16_f32 %0, %1, %2" : "=v"(r) : "v"(lo), "v"(hi));
    return r;
}
DEVINL unsigned short bfr(float f) {           // single f32 -> bf16 (RNE)
    return (unsigned short)(cvtpk(f, f) & 0xffffu);
}
DEVINL float bf2f(unsigned short u) {
    unsigned int w = (unsigned int)u << 16;
    return __builtin_bit_cast(float, w);
}
DEVINL void permswap(unsigned int& a, unsigned int& b) {
    asm("v_permlane32_swap_b32 %0, %1" : "+v"(a), "+v"(b));
}
DEVINL bf16x8 pack_frag(unsigned int w0, unsigned int w1, unsigned int w2, unsigned int w3) {
    u32x4 t; t[0] = w0; t[1] = w1; t[2] = w2; t[3] = w3;
    return __builtin_bit_cast(bf16x8, t);
}
DEVINL bf16x8 frag8_f32(const float* p) {      // 8 consecutive f32 -> bf16x8 frag
    f32x4 a = *reinterpret_cast<const f32x4*>(p);
    f32x4 b = *reinterpret_cast<const f32x4*>(p + 4);
    return pack_frag(cvtpk(a[0], a[1]), cvtpk(a[2], a[3]),
                     cvtpk(b[0], b[1]), cvtpk(b[2], b[3]));
}
// fp8 e4m3 helpers
DEVINL unsigned int fp8x4(float a, float b, float c, float d) {
    int r = __builtin_amdgcn_cvt_pk_fp8_f32(a, b, 0, false);   // bytes 0,1
    r = __builtin_amdgcn_cvt_pk_fp8_f32(c, d, r, true);        // bytes 2,3
    return (unsigned int)r;
}
DEVINL unsigned char fp8b(float f) {
    return (unsigned char)(__builtin_amdgcn_cvt_pk_fp8_f32(f, f, 0, false) & 0xFF);
}
DEVINL i32x8 cat8(i32x4 a, i32x4 b) {
    return __builtin_shufflevector(a, b, 0, 1, 2, 3, 4, 5, 6, 7);
}
// fp8 e4m3 MFMA, K=64, scales = 1.0 (e8m0 = 127 in every byte)
DEVINL f32x16 mfma8(i32x8 a, i32x8 b, f32x16 c) {
    return __builtin_amdgcn_mfma_scale_f32_32x32x64_f8f6f4(
        a, b, c, 0 /*cbsz: fp8*/, 0 /*blgp: fp8*/,
        0, 0x7F7F7F7F, 0, 0x7F7F7F7F);
}
// Schraudolph fast 2^x (fma + cvt; +-3% rel err, sub-dominant vs fp8's 6%).
// x=0 (pad rows) yields the same deterministic constant in flash and combine.
DEVINL float fexp2(float x) {
    float f = __builtin_fmaf(x, 8388608.0f, 1065713994.0f);   // 2^23, bias*2^23 + offset
    int i = (int)f;
    return __builtin_bit_cast(float, i);
}
// packed f32 add (v_pk_add_f32): 2 adds in one instruction
DEVINL f32x2 pkadd(f32x2 a, f32x2 b) {
    f32x2 r;
    asm("v_pk_add_f32 %0, %1, %2" : "=v"(r) : "v"(a), "v"(b));
    return r;
}

// ---------------------------------------------------------------------------
// prep: per 64-row tile: hidden = relu(K @ aW^T + b) via 32x32x16 bf16 MFMA
//       -> Khid fp8 [n][64]; K^T -> Vpan fp8 (panels: Vpan[n/32][64 d][32 nn],
//       each panel 2KB contiguous); column-sum partials (f32, exact).
//       Pad rows (n >= NKEYS) exact zeros.
// grid (NTIL, 2), block 256
// ---------------------------------------------------------------------------
__global__ __launch_bounds__(256) void prep_kernel(
    const float* __restrict__ user_emb, const float* __restrict__ item_emb,
    const float* __restrict__ uaW, const float* __restrict__ uab,
    const float* __restrict__ iaW, const float* __restrict__ iab,
    unsigned char* __restrict__ Khid, unsigned char* __restrict__ Vpan,
    float* __restrict__ csum)
{
    const int side = blockIdx.y;
    const int tile = blockIdx.x;
    const float* keys = (side == 0) ? item_emb : user_emb;
    const float* aW   = (side == 0) ? uaW : iaW;
    const float* ab   = (side == 0) ? uab : iab;
    unsigned char* Kh  = Khid + (size_t)side * NP * DIM;
    unsigned char* Vps = Vpan + (size_t)side * (NP / 32) * 2048;

    __shared__ float Kf[64][68];
    __shared__ float Wf[64][68];
    __shared__ float bl[64];

    const int t  = threadIdx.x;
    const int r  = t >> 2;
    const int c0 = (t & 3) * 16;

    {   // stage aW rows (f32)
        const float4* src = reinterpret_cast<const float4*>(aW + r * 64 + c0);
        float4* dst = reinterpret_cast<float4*>(&Wf[r][c0]);
        #pragma unroll
        for (int q = 0; q < 4; ++q) dst[q] = src[q];
        if (t < 64) bl[t] = ab[t];
    }
    {   // stage keys tile (zero pads)
        const int n = tile * 64 + r;
        float4* dst = reinterpret_cast<float4*>(&Kf[r][c0]);
        if (n < NKEYS) {
            const float4* src = reinterpret_cast<const float4*>(keys + (size_t)n * 64 + c0);
            #pragma unroll
            for (int q = 0; q < 4; ++q) dst[q] = src[q];
        } else {
            const float4 z = make_float4(0.f, 0.f, 0.f, 0.f);
            #pragma unroll
            for (int q = 0; q < 4; ++q) dst[q] = z;
        }
    }
    __syncthreads();

    {   // hidden 32x32 tile per wave via bf16 MFMA
        const int wv = t >> 6, lane = t & 63;
        const int c = lane & 31, hi = lane >> 5;
        const int n0 = (wv & 1) * 32, j0 = (wv >> 1) * 32;
        f32x16 acc{};
        #pragma unroll
        for (int ks = 0; ks < 4; ++ks) {
            bf16x8 af = frag8_f32(&Kf[n0 + c][ks * 16 + hi * 8]);
            bf16x8 bf_ = frag8_f32(&Wf[j0 + c][ks * 16 + hi * 8]);
            acc = __builtin_amdgcn_mfma_f32_32x32x16_bf16(af, bf_, acc, 0, 0, 0);
        }
        const float bj = bl[j0 + c];
        #pragma unroll
        for (int rr = 0; rr < 16; ++rr) {
            const int n  = n0 + (rr & 3) + 8 * (rr >> 2) + 4 * hi;
            const int gn = tile * 64 + n;
            float h = fmaxf(acc[rr] + bj, 0.f);
            if (gn >= NKEYS) h = 0.f;
            Kh[(size_t)gn * 64 + j0 + c] = fp8b(h);
        }
    }
    {   // Vpan fp8: thread: d = r, nn-cols c0..c0+15 within this 64-tile
        unsigned int pw[4];
        #pragma unroll
        for (int j = 0; j < 4; ++j)
            pw[j] = fp8x4(Kf[c0 + 4 * j][r],     Kf[c0 + 4 * j + 1][r],
                          Kf[c0 + 4 * j + 2][r], Kf[c0 + 4 * j + 3][r]);
        unsigned char* dst = Vps + ((size_t)(2 * tile + (c0 >> 5))) * 2048 + r * 32 + (c0 & 31);
        *reinterpret_cast<uint4*>(dst) = make_uint4(pw[0], pw[1], pw[2], pw[3]);
    }
    if (t < 64) {   // column partial sums (f32, exact keys)
        float s = 0.f;
        #pragma unroll 8
        for (int rr = 0; rr < 64; ++rr) s += Kf[rr][t];
        csum[((size_t)side * NTIL + tile) * 64 + t] = s;
    }
}

// grid (64, 2), block 64
__global__ __launch_bounds__(64) void sreduceA_kernel(const float* __restrict__ csum,
                                                      float* __restrict__ csum2)
{
    const int j = blockIdx.x, side = blockIdx.y, d = threadIdx.x;
    float s = 0.f;
    for (int idx = j; idx < NTIL; idx += 64)
        s += csum[((size_t)side * NTIL + idx) * 64 + d];
    csum2[((size_t)side * 64 + j) * 64 + d] = s;
}

// grid (2), block 64
__global__ __launch_bounds__(64) void sreduceB_kernel(const float* __restrict__ csum2,
                                                      float* __restrict__ Sbuf)
{
    const int side = blockIdx.x, d = threadIdx.x;
    float s = 0.f;
    #pragma unroll 8
    for (int j = 0; j < 64; ++j) s += csum2[((size_t)side * 64 + j) * 64 + d];
    Sbuf[side * 64 + d] = s;
}

// ---------------------------------------------------------------------------
// flash (MX-fp8, 128-n phases): block = 8 waves (512 thr), each wave a
//   32-query tile; block covers 256 q over one n-chunk of 3200 keys,
//   25 phases of 128 n (two sequential 64-n sub-steps per phase).
// LDS buffer (16KB) = two 8KB halves, each with the proven sub-layout:
//   K: st*2048 + qh*1024 + hi*512 + c*16  (K[st*32+c][d = 32hi + 16qh + 0..15])
//   V: 4096 + dblk*2048 + qh*1024 + hi*512 + c*16
//      (V[n = 32hi + 16qh + 0..15][d = 32dblk + c])
// A/B lane (hi,c): row/col = c, k = 32hi + byte j. C/D: col = lane&31,
//   row = (rr&3)+8(rr>>2)+4hi (verified, shape-determined).
// Staging: wave w stages 2KB/phase = 2 DMA (one per half): dest buf + h*8192 +
//   w*1024 + lane*16; src = gnext + h*4096 with the per-wave permuted base
//   (K: st*2048 + qh*16 + c*64 + hi*32; V: dblk*1024 + qh*16 + hi*2048 + c*32).
//   Advance 8192 B/phase (K: 128n x 64B; V: 4 panels x 2048B). Double-buffered,
//   DMA one full phase ahead; pre-barrier vmcnt(0) waits phase-old loads only.
// grid (NCH, 8, 2) = 512 blocks = 2.00 blocks/CU (no tail).
// ---------------------------------------------------------------------------
__global__ __launch_bounds__(512) void flash_kernel(
    const float* __restrict__ user_emb, const float* __restrict__ item_emb,
    const int* __restrict__ user_id, const int* __restrict__ item_id,
    const unsigned char* __restrict__ Khid, const unsigned char* __restrict__ Vpan,
    unsigned short* __restrict__ Opart, float* __restrict__ lpart)
{
    const int side  = blockIdx.z;
    const int chunk = blockIdx.x;
    const int qblk  = blockIdx.y;
    const int wave  = threadIdx.x >> 6;
    const int lane  = threadIdx.x & 63;
    const int c  = lane & 31;
    const int hi = lane >> 5;

    __shared__ __align__(16) unsigned char KV[2][16384];   // 2 x 16KB

    const float* emb = (side == 0) ? user_emb : item_emb;
    const int* ids   = (side == 0) ? user_id  : item_id;
    const unsigned char* Kh = Khid + ((size_t)side * NP + (size_t)chunk * CHROWS) * 64;
    const unsigned char* Vb = Vpan + ((size_t)side * (NP / 32) + (size_t)chunk * (CHROWS / 32)) * 2048;

    // ---- staging setup
    const unsigned char* gsrc;
    if (wave < 4) {
        const int st = wave >> 1, qh = wave & 1;
        gsrc = Kh + st * 2048 + qh * 16 + c * 64 + hi * 32;
    } else {
        const int dblk = (wave - 4) >> 1, qh = wave & 1;
        gsrc = Vb + dblk * 1024 + qh * 16 + hi * 2048 + c * 32;
    }

    const unsigned char* gnext = gsrc;      // source cursor for next ISSUE
    int ibuf = 0;                           // LDS buffer for next ISSUE
    auto ISSUE = [&]() {
        __builtin_amdgcn_global_load_lds(
            (const __attribute__((address_space(1))) unsigned int*)gnext,
            (__attribute__((address_space(3))) unsigned int*)&KV[ibuf][wave * 1024],
            16, 0, 0);
        __builtin_amdgcn_global_load_lds(
            (const __attribute__((address_space(1))) unsigned int*)(gnext + 4096),
            (__attribute__((address_space(3))) unsigned int*)&KV[ibuf][8192 + wave * 1024],
            16, 0, 0);
        gnext += 8192;
        ibuf ^= 1;
    };

    // ---- Q gather (32 floats/lane: d = 32hi .. 32hi+31)
    const int qtile = qblk * 256 + wave * 32;
    const int id = ids[qtile + c];
    const float* qrow = emb + (size_t)id * 64 + hi * 32;
    float4 qf[8];
    #pragma unroll
    for (int w = 0; w < 8; ++w)
        qf[w] = *reinterpret_cast<const float4*>(qrow + w * 4);

    ISSUE();            // phase 0 -> buf 0

    // pack Q fp8 (B-operand of swapped QK^T), scaled by log2(e)
    i32x8 bq;
    #pragma unroll
    for (int w = 0; w < 8; ++w)
        bq[w] = (int)fp8x4(qf[w].x * LOG2E, qf[w].y * LOG2E,
                           qf[w].z * LOG2E, qf[w].w * LOG2E);

    f32x16 o0{}, o1{};
    f32x2 lacc[8] = {};

    asm volatile("s_waitcnt vmcnt(0)" ::: "memory");   // phase-0 DMA done
    __builtin_amdgcn_s_barrier();

    for (int p = 0; p < NPH; ++p) {
        if (p + 1 < NPH) ISSUE();

        const unsigned char* Bp0 = &KV[p & 1][0];
        #pragma unroll
        for (int h = 0; h < 2; ++h) {
            const unsigned char* Bp = Bp0 + h * 8192;
            const int fo = hi * 512 + c * 16;

            // K A-frags (2 st), 2 x b128 each
            i32x8 ak0 = cat8(*reinterpret_cast<const i32x4*>(Bp + fo),
                             *reinterpret_cast<const i32x4*>(Bp + 1024 + fo));
            i32x8 ak1 = cat8(*reinterpret_cast<const i32x4*>(Bp + 2048 + fo),
                             *reinterpret_cast<const i32x4*>(Bp + 3072 + fo));

            __builtin_amdgcn_s_setprio(1);
            f32x16 z{};
            f32x16 s0 = mfma8(ak0, bq, z);     // n = h*64 + 0..31
            f32x16 s1 = mfma8(ak1, bq, z);     // n = h*64 + 32..63
            __builtin_amdgcn_s_setprio(0);

            // V B-frags (2 dblk)
            i32x8 bv0 = cat8(*reinterpret_cast<const i32x4*>(Bp + 4096 + fo),
                             *reinterpret_cast<const i32x4*>(Bp + 5120 + fo));
            i32x8 bv1 = cat8(*reinterpret_cast<const i32x4*>(Bp + 6144 + fo),
                             *reinterpret_cast<const i32x4*>(Bp + 7168 + fo));

            // P = fexp2(S)
            #pragma unroll
            for (int rr = 0; rr < 16; ++rr) s0[rr] = fexp2(s0[rr]);
            #pragma unroll
            for (int rr = 0; rr < 16; ++rr) s1[rr] = fexp2(s1[rr]);

            // l accumulate via packed f32 adds
            #pragma unroll
            for (int g = 0; g < 8; ++g) {
                f32x2 a; a[0] = s0[2 * g]; a[1] = s0[2 * g + 1];
                f32x2 b; b[0] = s1[2 * g]; b[1] = s1[2 * g + 1];
                lacc[g] = pkadd(lacc[g], pkadd(a, b));
            }

            // P fp8 A-frag via cvt_pk_fp8 + permlane32_swap
            unsigned int p0[4], p1[4];
            #pragma unroll
            for (int g = 0; g < 4; ++g) {
                p0[g] = fp8x4(s0[4 * g], s0[4 * g + 1], s0[4 * g + 2], s0[4 * g + 3]);
                p1[g] = fp8x4(s1[4 * g], s1[4 * g + 1], s1[4 * g + 2], s1[4 * g + 3]);
                permswap(p0[g], p1[g]);
            }
            i32x8 pa;
            pa[0] = (int)p0[0]; pa[1] = (int)p1[0];
            pa[2] = (int)p0[1]; pa[3] = (int)p1[1];
            pa[4] = (int)p0[2]; pa[5] = (int)p1[2];
            pa[6] = (int)p0[3]; pa[7] = (int)p1[3];

            __builtin_amdgcn_s_setprio(1);
            o0 = mfma8(pa, bv0, o0);           // d = 0..31
            o1 = mfma8(pa, bv1, o1);           // d = 32..63
            __builtin_amdgcn_s_setprio(0);
        }

        if (p + 1 < NPH) {
            // own 2 DMAs for p+1 were issued a full (128-n) phase ago
            asm volatile("s_waitcnt vmcnt(0)" ::: "memory");
            __builtin_amdgcn_s_barrier();
        }
    }

    float ls = 0.f;
    #pragma unroll
    for (int g = 0; g < 8; ++g) ls += lacc[g][0] + lacc[g][1];
    ls += __shfl_xor(ls, 32);   // lane c now holds l[qtile+c] for this chunk

    unsigned short* Op = Opart + (((size_t)(side * NCH + chunk)) * BQ + qtile) * 64;
    #pragma unroll
    for (int rr = 0; rr < 16; ++rr) {
        const int q = (rr & 3) + 8 * (rr >> 2) + 4 * hi;
        Op[q * 64 + c]      = bfr(o0[rr]);
        Op[q * 64 + 32 + c] = bfr(o1[rr]);
    }
    if (hi == 0)
        lpart[((size_t)(side * NCH + chunk)) * BQ + qtile + c] = ls;
}

// ---------------------------------------------------------------------------
// combine: O = sum(Opart)/(sum(lpart) - PADCNT*fexp2(0)); q2 = e + O;
//          out = leaky_relu((q2+S)@W1^T + (q2*S)@W2^T); og = [e, out]
// grid (2*BQ), block 64
// ---------------------------------------------------------------------------
__global__ __launch_bounds__(64) void combine_kernel(
    const float* __restrict__ user_emb, const float* __restrict__ item_emb,
    const int* __restrict__ user_id, const int* __restrict__ item_id,
    const float* __restrict__ uW1, const float* __restrict__ uW2,
    const float* __restrict__ iW1, const float* __restrict__ iW2,
    const unsigned short* __restrict__ Opart, const float* __restrict__ lpart,
    const float* __restrict__ Sbuf,
    float* __restrict__ Aog, float* __restrict__ Bog)
{
    const int bid  = blockIdx.x;
    const int side = bid >> 11;
    const int q    = bid & (BQ - 1);
    const int d    = threadIdx.x;

    const unsigned short* Ob = Opart + ((size_t)side * NCH * BQ + q) * 64 + d;
    float num = 0.f;
    #pragma unroll 8
    for (int ch = 0; ch < NCH; ++ch)
        num += bf2f(Ob[(size_t)ch * BQ * 64]);
    const float* lb = lpart + (size_t)side * NCH * BQ + q;
    // each pad key contributed exactly fexp2(0) to l (same instruction sequence)
    float lsum = -PADCNT * fexp2(0.0f);
    #pragma unroll 8
    for (int ch = 0; ch < NCH; ++ch)
        lsum += lb[(size_t)ch * BQ];

    const int id = ((side == 0) ? user_id : item_id)[q];
    const float* emb = (side == 0) ? user_emb : item_emb;
    const float e  = emb[(size_t)id * 64 + d];
    const float q2 = e + num / lsum;
    const float Sd = Sbuf[side * 64 + d];

    __shared__ float a1[64], a2[64];
    a1[d] = q2 + Sd;
    a2[d] = q2 * Sd;
    __syncthreads();

    const float* W1 = (side == 0) ? uW1 : iW1;
    const float* W2 = (side == 0) ? uW2 : iW2;
    float acc = 0.f;
    #pragma unroll 8
    for (int dd = 0; dd < 64; ++dd)
        acc += a1[dd] * W1[d * 64 + dd] + a2[dd] * W2[d * 64 + dd];
    const float out = (acc >= 0.f) ? acc : 0.01f * acc;

    float* og = (side == 0) ? Aog : Bog;
    og[(size_t)q * 128 + d]      = e;
    og[(size_t)q * 128 + 64 + d] = out;
}

// final stage 1: grid 32, block 256; block b: t-rows [64b, 64b+64), LDS-tiled,
// partial[b][i][j] = sum_t Aog[t][i]*Bog[t][j]
__global__ __launch_bounds__(256) void final1_kernel(
    const float* __restrict__ Aog, const float* __restrict__ Bog, float* __restrict__ part)
{
    const int b = blockIdx.x;
    const int t = threadIdx.x;
    __shared__ float As[64][128];
    __shared__ float Bs[64][128];
    {
        float* Asf = &As[0][0];
        float* Bsf = &Bs[0][0];
        const float* Ab = Aog + (size_t)b * 64 * 128;
        const float* Bb = Bog + (size_t)b * 64 * 128;
        #pragma unroll
        for (int qq = 0; qq < 8; ++qq) {
            const int off = qq * 1024 + t * 4;
            *reinterpret_cast<float4*>(Asf + off) = *reinterpret_cast<const float4*>(Ab + off);
            *reinterpret_cast<float4*>(Bsf + off) = *reinterpret_cast<const float4*>(Bb + off);
        }
    }
    __syncthreads();

    const int i0 = (t >> 4) * 8, j0 = (t & 15) * 8;
    float acc[8][8] = {};
    for (int k = 0; k < 64; ++k) {
        float av[8], bv[8];
        *reinterpret_cast<f32x4*>(&av[0]) = *reinterpret_cast<const f32x4*>(&As[k][i0]);
        *reinterpret_cast<f32x4*>(&av[4]) = *reinterpret_cast<const f32x4*>(&As[k][i0 + 4]);
        *reinterpret_cast<f32x4*>(&bv[0]) = *reinterpret_cast<const f32x4*>(&Bs[k][j0]);
        *reinterpret_cast<f32x4*>(&bv[4]) = *reinterpret_cast<const f32x4*>(&Bs[k][j0 + 4]);
        #pragma unroll
        for (int ii = 0; ii < 8; ++ii)
            #pragma unroll
            for (int jj = 0; jj < 8; ++jj)
                acc[ii][jj] += av[ii] * bv[jj];
    }
    float* P = part + (size_t)b * 128 * 128;
    #pragma unroll
    for (int ii = 0; ii < 8; ++ii) {
        *reinterpret_cast<float4*>(P + (i0 + ii) * 128 + j0)     = *reinterpret_cast<float4*>(&acc[ii][0]);
        *reinterpret_cast<float4*>(P + (i0 + ii) * 128 + j0 + 4) = *reinterpret_cast<float4*>(&acc[ii][4]);
    }
}

// final stage 2: grid 128, block 128: out[i][j] = sum_b partial[b][i][j]
__global__ __launch_bounds__(128) void final2_kernel(const float* __restrict__ part,
                                                     float* __restrict__ out)
{
    const int i = blockIdx.x, j = threadIdx.x;
    float s = 0.f;
    #pragma unroll 8
    for (int b = 0; b < 32; ++b) s += part[(size_t)b * 128 * 128 + i * 128 + j];
    out[i * 128 + j] = s;
}

extern "C" void kernel_launch(void* const* d_in, const int* in_sizes, int n_in,
                              void* d_out, int out_size, void* d_ws, size_t ws_size,
                              hipStream_t stream)
{
    (void)in_sizes; (void)n_in; (void)out_size; (void)ws_size;
    const float* user_emb = (const float*)d_in[0];
    const float* item_emb = (const float*)d_in[1];
    const float* uaW = (const float*)d_in[2];
    const float* uab = (const float*)d_in[3];
    const float* uW1 = (const float*)d_in[4];
    const float* uW2 = (const float*)d_in[5];
    const float* iaW = (const float*)d_in[6];
    const float* iab = (const float*)d_in[7];
    const float* iW1 = (const float*)d_in[8];
    const float* iW2 = (const float*)d_in[9];
    const int* user_id = (const int*)d_in[10];
    const int* item_id = (const int*)d_in[11];
    // d_in[12], d_in[13]: arange identity gathers -- no-ops.

    char* ws = (char*)d_ws;
    size_t off = 0;
    auto alloc = [&](size_t bytes) -> void* {
        void* p = ws + off;
        off = (off + bytes + 255) & ~(size_t)255;
        return p;
    };
    unsigned char* Khid8 = (unsigned char*)alloc((size_t)2 * NP * DIM);
    unsigned char* Vpan8 = (unsigned char*)alloc((size_t)2 * (NP / 32) * 2048);
    float* csum  = (float*)alloc((size_t)2 * NTIL * 64 * 4);
    float* csum2 = (float*)alloc((size_t)2 * 64 * 64 * 4);
    float* Sbuf  = (float*)alloc((size_t)2 * 64 * 4);
    unsigned short* Opart = (unsigned short*)alloc((size_t)2 * NCH * BQ * 64 * 2);
    float* lpart = (float*)alloc((size_t)2 * NCH * BQ * 4);
    float* Aog   = (float*)alloc((size_t)BQ * 128 * 4);
    float* Bog   = (float*)alloc((size_t)BQ * 128 * 4);
    float* Fpart = (float*)alloc((size_t)32 * 128 * 128 * 4);

    prep_kernel<<<dim3(NTIL, 2), 256, 0, stream>>>(user_emb, item_emb, uaW, uab, iaW, iab,
                                                   Khid8, Vpan8, csum);
    sreduceA_kernel<<<dim3(64, 2), 64, 0, stream>>>(csum, csum2);
    sreduceB_kernel<<<2, 64, 0, stream>>>(csum2, Sbuf);
    flash_kernel<<<dim3(NCH, BQ / 256, 2), 512, 0, stream>>>(user_emb, item_emb, user_id, item_id,
                                                             Khid8, Vpan8, Opart, lpart);
    combine_kernel<<<2 * BQ, 64, 0, stream>>>(user_emb, item_emb, user_id, item_id,
                                              uW1, uW2, iW1, iW2, Opart, lpart, Sbuf, Aog, Bog);
    final1_kernel<<<32, 256, 0, stream>>>(Aog, Bog, Fpart);
    final2_kernel<<<128, 128, 0, stream>>>(Fpart, (float*)d_out);
}

// Round 14
// 133.425 us; speedup vs baseline: 1.1149x; 1.1149x over previous
//
#include <hip/hip_runtime.h>

// ANCF recommender on MI355X.
// prep (MFMA hidden -> Khid fp8; keys^T -> Vpan fp8 n-panels; colsum partials)
//  -> sreduceA/B (S = colsum, 2-stage tree) ; wtrans (W1/W2 -> W^T, once)
//  -> flash (R12 config: MX-fp8 mfma_scale 32x32x64, 64-n phases, 2x8KB LDS,
//            1 DMA/wave/phase one phase ahead, raw s_barrier, 8-wave blocks,
//            grid 1024 = 4 blocks/CU, VGPR 64 = 8 waves/SIMD. Outputs now
//            q-major: Opart[side][q][ch][d], lpart[side][q][ch].)
//  -> combine (4-wave blocks, one q per wave: contiguous 8KB Opart row,
//              shfl-allreduce lsum, transposed-W coalesced epilogue)
//  -> final1/2 (128x128 = og_user^T @ og_item, 128-block k-split)
// Workspace required: ~75 MB.

typedef __bf16 bf16x8 __attribute__((ext_vector_type(8)));
typedef float f32x2 __attribute__((ext_vector_type(2)));
typedef float f32x4 __attribute__((ext_vector_type(4)));
typedef float f32x16 __attribute__((ext_vector_type(16)));
typedef unsigned int u32x4 __attribute__((ext_vector_type(4)));
typedef int i32x4 __attribute__((ext_vector_type(4)));
typedef int i32x8 __attribute__((ext_vector_type(8)));

static constexpr int NKEYS  = 100000;
static constexpr int NP     = 102400;          // 64 chunks * 1600 rows
static constexpr int DIM    = 64;
static constexpr int BQ     = 2048;
static constexpr int NCH    = 64;              // grid 64*8*2 = 1024 = 4 blocks/CU
static constexpr int CHROWS = NP / NCH;        // 1600
static constexpr int NPH    = CHROWS / 64;     // 25 phases of 64 n
static constexpr int NTIL   = NP / 64;         // 1600
static constexpr float PADCNT = float(NP - NKEYS);   // 2400 pads, each adds fexp2(0) to l
static constexpr float LOG2E  = 1.44269504088896340736f;

#define DEVINL __device__ __forceinline__

DEVINL unsigned int cvtpk(float lo, float hi) {
    unsigned int r;
    asm("v_cvt_pk_bf16_f32 %0, %1, %2" : "=v"(r) : "v"(lo), "v"(hi));
    return r;
}
DEVINL unsigned short bfr(float f) {           // single f32 -> bf16 (RNE)
    return (unsigned short)(cvtpk(f, f) & 0xffffu);
}
DEVINL float bf2f(unsigned short u) {
    unsigned int w = (unsigned int)u << 16;
    return __builtin_bit_cast(float, w);
}
DEVINL void permswap(unsigned int& a, unsigned int& b) {
    asm("v_permlane32_swap_b32 %0, %1" : "+v"(a), "+v"(b));
}
DEVINL bf16x8 pack_frag(unsigned int w0, unsigned int w1, unsigned int w2, unsigned int w3) {
    u32x4 t; t[0] = w0; t[1] = w1; t[2] = w2; t[3] = w3;
    return __builtin_bit_cast(bf16x8, t);
}
DEVINL bf16x8 frag8_f32(const float* p) {      // 8 consecutive f32 -> bf16x8 frag
    f32x4 a = *reinterpret_cast<const f32x4*>(p);
    f32x4 b = *reinterpret_cast<const f32x4*>(p + 4);
    return pack_frag(cvtpk(a[0], a[1]), cvtpk(a[2], a[3]),
                     cvtpk(b[0], b[1]), cvtpk(b[2], b[3]));
}
// fp8 e4m3 helpers
DEVINL unsigned int fp8x4(float a, float b, float c, float d) {
    int r = __builtin_amdgcn_cvt_pk_fp8_f32(a, b, 0, false);   // bytes 0,1
    r = __builtin_amdgcn_cvt_pk_fp8_f32(c, d, r, true);        // bytes 2,3
    return (unsigned int)r;
}
DEVINL unsigned char fp8b(float f) {
    return (unsigned char)(__builtin_amdgcn_cvt_pk_fp8_f32(f, f, 0, false) & 0xFF);
}
DEVINL i32x8 cat8(i32x4 a, i32x4 b) {
    return __builtin_shufflevector(a, b, 0, 1, 2, 3, 4, 5, 6, 7);
}
// fp8 e4m3 MFMA, K=64, scales = 1.0 (e8m0 = 127 in every byte)
DEVINL f32x16 mfma8(i32x8 a, i32x8 b, f32x16 c) {
    return __builtin_amdgcn_mfma_scale_f32_32x32x64_f8f6f4(
        a, b, c, 0 /*cbsz: fp8*/, 0 /*blgp: fp8*/,
        0, 0x7F7F7F7F, 0, 0x7F7F7F7F);
}
// Schraudolph fast 2^x (fma + cvt; +-3% rel err, sub-dominant vs fp8's 6%).
// x=0 (pad rows) yields the same deterministic constant in flash and combine.
DEVINL float fexp2(float x) {
    float f = __builtin_fmaf(x, 8388608.0f, 1065713994.0f);
    int i = (int)f;
    return __builtin_bit_cast(float, i);
}
// packed f32 add (v_pk_add_f32): 2 adds in one instruction
DEVINL f32x2 pkadd(f32x2 a, f32x2 b) {
    f32x2 r;
    asm("v_pk_add_f32 %0, %1, %2" : "=v"(r) : "v"(a), "v"(b));
    return r;
}

// ---------------------------------------------------------------------------
// prep: per 64-row tile: hidden = relu(K @ aW^T + b) via 32x32x16 bf16 MFMA
//       -> Khid fp8 [n][64]; K^T -> Vpan fp8 (panels: Vpan[n/32][64 d][32 nn],
//       each panel 2KB contiguous); column-sum partials (f32, exact).
//       Pad rows (n >= NKEYS) exact zeros.
// grid (NTIL, 2), block 256
// ---------------------------------------------------------------------------
__global__ __launch_bounds__(256) void prep_kernel(
    const float* __restrict__ user_emb, const float* __restrict__ item_emb,
    const float* __restrict__ uaW, const float* __restrict__ uab,
    const float* __restrict__ iaW, const float* __restrict__ iab,
    unsigned char* __restrict__ Khid, unsigned char* __restrict__ Vpan,
    float* __restrict__ csum)
{
    const int side = blockIdx.y;
    const int tile = blockIdx.x;
    const float* keys = (side == 0) ? item_emb : user_emb;
    const float* aW   = (side == 0) ? uaW : iaW;
    const float* ab   = (side == 0) ? uab : iab;
    unsigned char* Kh  = Khid + (size_t)side * NP * DIM;
    unsigned char* Vps = Vpan + (size_t)side * (NP / 32) * 2048;

    __shared__ float Kf[64][68];
    __shared__ float Wf[64][68];
    __shared__ float bl[64];

    const int t  = threadIdx.x;
    const int r  = t >> 2;
    const int c0 = (t & 3) * 16;

    {   // stage aW rows (f32)
        const float4* src = reinterpret_cast<const float4*>(aW + r * 64 + c0);
        float4* dst = reinterpret_cast<float4*>(&Wf[r][c0]);
        #pragma unroll
        for (int q = 0; q < 4; ++q) dst[q] = src[q];
        if (t < 64) bl[t] = ab[t];
    }
    {   // stage keys tile (zero pads)
        const int n = tile * 64 + r;
        float4* dst = reinterpret_cast<float4*>(&Kf[r][c0]);
        if (n < NKEYS) {
            const float4* src = reinterpret_cast<const float4*>(keys + (size_t)n * 64 + c0);
            #pragma unroll
            for (int q = 0; q < 4; ++q) dst[q] = src[q];
        } else {
            const float4 z = make_float4(0.f, 0.f, 0.f, 0.f);
            #pragma unroll
            for (int q = 0; q < 4; ++q) dst[q] = z;
        }
    }
    __syncthreads();

    {   // hidden 32x32 tile per wave via bf16 MFMA
        const int wv = t >> 6, lane = t & 63;
        const int c = lane & 31, hi = lane >> 5;
        const int n0 = (wv & 1) * 32, j0 = (wv >> 1) * 32;
        f32x16 acc{};
        #pragma unroll
        for (int ks = 0; ks < 4; ++ks) {
            bf16x8 af = frag8_f32(&Kf[n0 + c][ks * 16 + hi * 8]);
            bf16x8 bf_ = frag8_f32(&Wf[j0 + c][ks * 16 + hi * 8]);
            acc = __builtin_amdgcn_mfma_f32_32x32x16_bf16(af, bf_, acc, 0, 0, 0);
        }
        const float bj = bl[j0 + c];
        #pragma unroll
        for (int rr = 0; rr < 16; ++rr) {
            const int n  = n0 + (rr & 3) + 8 * (rr >> 2) + 4 * hi;
            const int gn = tile * 64 + n;
            float h = fmaxf(acc[rr] + bj, 0.f);
            if (gn >= NKEYS) h = 0.f;
            Kh[(size_t)gn * 64 + j0 + c] = fp8b(h);
        }
    }
    {   // Vpan fp8: thread: d = r, nn-cols c0..c0+15 within this 64-tile
        unsigned int pw[4];
        #pragma unroll
        for (int j = 0; j < 4; ++j)
            pw[j] = fp8x4(Kf[c0 + 4 * j][r],     Kf[c0 + 4 * j + 1][r],
                          Kf[c0 + 4 * j + 2][r], Kf[c0 + 4 * j + 3][r]);
        unsigned char* dst = Vps + ((size_t)(2 * tile + (c0 >> 5))) * 2048 + r * 32 + (c0 & 31);
        *reinterpret_cast<uint4*>(dst) = make_uint4(pw[0], pw[1], pw[2], pw[3]);
    }
    if (t < 64) {   // column partial sums (f32, exact keys)
        float s = 0.f;
        #pragma unroll 8
        for (int rr = 0; rr < 64; ++rr) s += Kf[rr][t];
        csum[((size_t)side * NTIL + tile) * 64 + t] = s;
    }
}

// grid (64, 2), block 64
__global__ __launch_bounds__(64) void sreduceA_kernel(const float* __restrict__ csum,
                                                      float* __restrict__ csum2)
{
    const int j = blockIdx.x, side = blockIdx.y, d = threadIdx.x;
    float s = 0.f;
    for (int idx = j; idx < NTIL; idx += 64)
        s += csum[((size_t)side * NTIL + idx) * 64 + d];
    csum2[((size_t)side * 64 + j) * 64 + d] = s;
}

// grid (2), block 64
__global__ __launch_bounds__(64) void sreduceB_kernel(const float* __restrict__ csum2,
                                                      float* __restrict__ Sbuf)
{
    const int side = blockIdx.x, d = threadIdx.x;
    float s = 0.f;
    #pragma unroll 8
    for (int j = 0; j < 64; ++j) s += csum2[((size_t)side * 64 + j) * 64 + d];
    Sbuf[side * 64 + d] = s;
}

// grid 4, block 256: WT[m][dd][j] = W_m[j][dd]  (m: uW1,uW2,iW1,iW2)
__global__ __launch_bounds__(256) void wtrans_kernel(
    const float* __restrict__ uW1, const float* __restrict__ uW2,
    const float* __restrict__ iW1, const float* __restrict__ iW2,
    float* __restrict__ WT)
{
    const float* W = (blockIdx.x == 0) ? uW1 : (blockIdx.x == 1) ? uW2
                   : (blockIdx.x == 2) ? iW1 : iW2;
    float* T = WT + (size_t)blockIdx.x * 4096;
    const int t = threadIdx.x;
    const int j = t >> 2;
    const int dd0 = (t & 3) * 16;
    #pragma unroll
    for (int k = 0; k < 16; ++k)
        T[(dd0 + k) * 64 + j] = W[j * 64 + dd0 + k];
}

// ---------------------------------------------------------------------------
// flash (MX-fp8, R12 config): block = 8 waves (512 thr), each wave a 32-query
//   tile; block covers 256 q over one n-chunk of 1600 keys, 25 phases of 64 n.
// Per phase per wave: 2 QK mfma_scale_32x32x64 (K=64 = full d), 32 fexp2,
//   16 pk_add, 16 cvt_pk_fp8 + 4 permlane32_swap, 2 PV mfma_scale (K=64 =
//   full phase-n), 8 ds_read_b128, 1 DMA issue.
// LDS per buffer (8KB, bytes): K: st*2048 + qh*1024 + hi*512 + c*16
//   (K[st*32+c][d=32hi+16qh+0..15]); V: 4096 + dblk*2048 + qh*1024 + hi*512 +
//   c*16 (V[n=32hi+16qh+0..15][d=32dblk+c]).
// A/B lane (hi,c): row/col = c, k = 32hi + byte j. C/D: col = lane&31,
//   row = (rr&3)+8(rr>>2)+4hi (verified, shape-determined).
// Staging: wave w: dest = buf + w*1024 + lane*16; src K (w<4: st=w>>1, qh=w&1):
//   st*2048 + qh*16 + c*64 + hi*32; src V (w>=4: dblk=(w-4)>>1):
//   dblk*1024 + qh*16 + hi*2048 + c*32. Advance 4096 B/phase. Double-buffered,
//   DMA one full phase ahead; pre-barrier vmcnt(0) waits phase-old loads only.
// Outputs q-major: Opart[side][q][ch][d] (write coalescing unchanged: 64B runs),
//   lpart[side][q][ch].
// grid (NCH, 8, 2) = 1024 blocks = 4 blocks/CU.
// ---------------------------------------------------------------------------
__global__ __launch_bounds__(512) void flash_kernel(
    const float* __restrict__ user_emb, const float* __restrict__ item_emb,
    const int* __restrict__ user_id, const int* __restrict__ item_id,
    const unsigned char* __restrict__ Khid, const unsigned char* __restrict__ Vpan,
    unsigned short* __restrict__ Opart, float* __restrict__ lpart)
{
    const int side  = blockIdx.z;
    const int chunk = blockIdx.x;
    const int qblk  = blockIdx.y;
    const int wave  = threadIdx.x >> 6;
    const int lane  = threadIdx.x & 63;
    const int c  = lane & 31;
    const int hi = lane >> 5;

    __shared__ __align__(16) unsigned char KV[2][8192];   // 2 x 8KB

    const float* emb = (side == 0) ? user_emb : item_emb;
    const int* ids   = (side == 0) ? user_id  : item_id;
    const unsigned char* Kh = Khid + ((size_t)side * NP + (size_t)chunk * CHROWS) * 64;
    const unsigned char* Vb = Vpan + ((size_t)side * (NP / 32) + (size_t)chunk * (CHROWS / 32)) * 2048;

    // ---- staging setup: wave w stages LDS bytes [w*1024, w*1024+1024) per phase
    const unsigned char* gsrc;
    if (wave < 4) {
        const int st = wave >> 1, qh = wave & 1;
        gsrc = Kh + st * 2048 + qh * 16 + c * 64 + hi * 32;
    } else {
        const int dblk = (wave - 4) >> 1, qh = wave & 1;
        gsrc = Vb + dblk * 1024 + qh * 16 + hi * 2048 + c * 32;
    }

    const unsigned char* gnext = gsrc;      // source cursor for next ISSUE
    int ibuf = 0;                           // LDS buffer for next ISSUE
    auto ISSUE = [&]() {
        __builtin_amdgcn_global_load_lds(
            (const __attribute__((address_space(1))) unsigned int*)gnext,
            (__attribute__((address_space(3))) unsigned int*)&KV[ibuf][wave * 1024],
            16, 0, 0);
        gnext += 4096;
        ibuf ^= 1;
    };

    // ---- Q gather (32 floats/lane: d = 32hi .. 32hi+31)
    const int qtile = qblk * 256 + wave * 32;
    const int id = ids[qtile + c];
    const float* qrow = emb + (size_t)id * 64 + hi * 32;
    float4 qf[8];
    #pragma unroll
    for (int w = 0; w < 8; ++w)
        qf[w] = *reinterpret_cast<const float4*>(qrow + w * 4);

    ISSUE();            // phase 0 -> buf 0

    // pack Q fp8 (B-operand of swapped QK^T), scaled by log2(e)
    i32x8 bq;
    #pragma unroll
    for (int w = 0; w < 8; ++w)
        bq[w] = (int)fp8x4(qf[w].x * LOG2E, qf[w].y * LOG2E,
                           qf[w].z * LOG2E, qf[w].w * LOG2E);

    f32x16 o0{}, o1{};
    f32x2 lacc[8] = {};

    asm volatile("s_waitcnt vmcnt(0)" ::: "memory");   // phase-0 DMA done
    __builtin_amdgcn_s_barrier();

    for (int p = 0; p < NPH; ++p) {
        if (p + 1 < NPH) ISSUE();

        const unsigned char* Bp = &KV[p & 1][0];
        const int fo = hi * 512 + c * 16;

        // K A-frags (2 st), 2 x b128 each
        i32x8 ak0 = cat8(*reinterpret_cast<const i32x4*>(Bp + fo),
                         *reinterpret_cast<const i32x4*>(Bp + 1024 + fo));
        i32x8 ak1 = cat8(*reinterpret_cast<const i32x4*>(Bp + 2048 + fo),
                         *reinterpret_cast<const i32x4*>(Bp + 3072 + fo));

        __builtin_amdgcn_s_setprio(1);
        f32x16 z{};
        f32x16 s0 = mfma8(ak0, bq, z);     // st0: n = 0..31
        f32x16 s1 = mfma8(ak1, bq, z);     // st1: n = 32..63
        __builtin_amdgcn_s_setprio(0);

        // V B-frags (2 dblk)
        i32x8 bv0 = cat8(*reinterpret_cast<const i32x4*>(Bp + 4096 + fo),
                         *reinterpret_cast<const i32x4*>(Bp + 5120 + fo));
        i32x8 bv1 = cat8(*reinterpret_cast<const i32x4*>(Bp + 6144 + fo),
                         *reinterpret_cast<const i32x4*>(Bp + 7168 + fo));

        // P = fexp2(S)
        #pragma unroll
        for (int rr = 0; rr < 16; ++rr) s0[rr] = fexp2(s0[rr]);
        #pragma unroll
        for (int rr = 0; rr < 16; ++rr) s1[rr] = fexp2(s1[rr]);

        // l accumulate via packed f32 adds
        #pragma unroll
        for (int g = 0; g < 8; ++g) {
            f32x2 a; a[0] = s0[2 * g]; a[1] = s0[2 * g + 1];
            f32x2 b; b[0] = s1[2 * g]; b[1] = s1[2 * g + 1];
            lacc[g] = pkadd(lacc[g], pkadd(a, b));
        }

        // P fp8 A-frag via cvt_pk_fp8 + permlane32_swap
        unsigned int p0[4], p1[4];
        #pragma unroll
        for (int g = 0; g < 4; ++g) {
            p0[g] = fp8x4(s0[4 * g], s0[4 * g + 1], s0[4 * g + 2], s0[4 * g + 3]);
            p1[g] = fp8x4(s1[4 * g], s1[4 * g + 1], s1[4 * g + 2], s1[4 * g + 3]);
            permswap(p0[g], p1[g]);
        }
        i32x8 pa;
        pa[0] = (int)p0[0]; pa[1] = (int)p1[0];
        pa[2] = (int)p0[1]; pa[3] = (int)p1[1];
        pa[4] = (int)p0[2]; pa[5] = (int)p1[2];
        pa[6] = (int)p0[3]; pa[7] = (int)p1[3];

        __builtin_amdgcn_s_setprio(1);
        o0 = mfma8(pa, bv0, o0);           // d = 0..31
        o1 = mfma8(pa, bv1, o1);           // d = 32..63
        __builtin_amdgcn_s_setprio(0);

        if (p + 1 < NPH) {
            asm volatile("s_waitcnt vmcnt(0)" ::: "memory");
            __builtin_amdgcn_s_barrier();
        }
    }

    float ls = 0.f;
    #pragma unroll
    for (int g = 0; g < 8; ++g) ls += lacc[g][0] + lacc[g][1];
    ls += __shfl_xor(ls, 32);   // lane c now holds l[qtile+c] for this chunk

    // q-major outputs
    unsigned short* Op = Opart + (((size_t)(side * BQ + qtile)) * NCH + chunk) * 64;
    #pragma unroll
    for (int rr = 0; rr < 16; ++rr) {
        const int q = (rr & 3) + 8 * (rr >> 2) + 4 * hi;
        Op[(size_t)q * NCH * 64 + c]      = bfr(o0[rr]);
        Op[(size_t)q * NCH * 64 + 32 + c] = bfr(o1[rr]);
    }
    if (hi == 0)
        lpart[((size_t)(side * BQ + qtile + c)) * NCH + chunk] = ls;
}

// ---------------------------------------------------------------------------
// combine: 4-wave blocks, one q per wave (lane = output dim j).
//   num[j] = sum_ch Opart[side][q][ch][j]   (contiguous 8KB row, coalesced)
//   lsum   = shfl-allreduce of lpart[side][q][ch] (one coalesced 256B load)
//   q2 = e + num/(lsum - PADCNT*fexp2(0));
//   out = leaky_relu(sum_dd a1[dd]*W1T[dd][j] + a2[dd]*W2T[dd][j])  (coalesced)
// grid (2*BQ/4) = 1024, block 256
// ---------------------------------------------------------------------------
__global__ __launch_bounds__(256) void combine_kernel(
    const float* __restrict__ user_emb, const float* __restrict__ item_emb,
    const int* __restrict__ user_id, const int* __restrict__ item_id,
    const float* __restrict__ WT,
    const unsigned short* __restrict__ Opart, const float* __restrict__ lpart,
    const float* __restrict__ Sbuf,
    float* __restrict__ Aog, float* __restrict__ Bog)
{
    const int bid  = blockIdx.x;
    const int side = bid >> 9;
    const int wave = threadIdx.x >> 6;
    const int lane = threadIdx.x & 63;
    const int q    = ((bid & 511) << 2) + wave;
    const int j    = lane;

    const unsigned short* Ob = Opart + ((size_t)(side * BQ + q)) * (NCH * 64) + j;
    float num = 0.f;
    #pragma unroll 8
    for (int ch = 0; ch < NCH; ++ch)
        num += bf2f(Ob[ch * 64]);

    float lv = lpart[((size_t)(side * BQ + q)) * NCH + lane];
    #pragma unroll
    for (int m = 32; m >= 1; m >>= 1) lv += __shfl_xor(lv, m);
    const float lsum = lv - PADCNT * fexp2(0.0f);

    const int id = ((side == 0) ? user_id : item_id)[q];
    const float* emb = (side == 0) ? user_emb : item_emb;
    const float e  = emb[(size_t)id * 64 + j];
    const float q2 = e + num / lsum;
    const float Sd = Sbuf[side * 64 + j];

    __shared__ float a1s[4][64], a2s[4][64];
    a1s[wave][j] = q2 + Sd;
    a2s[wave][j] = q2 * Sd;
    // intra-wave LDS write->read: lockstep, compiler inserts lgkmcnt

    const float* W1T = WT + (size_t)side * 8192;        // [dd][j]
    const float* W2T = W1T + 4096;
    float acc = 0.f;
    #pragma unroll 8
    for (int dd = 0; dd < 64; ++dd)
        acc += a1s[wave][dd] * W1T[dd * 64 + j] + a2s[wave][dd] * W2T[dd * 64 + j];
    const float out = (acc >= 0.f) ? acc : 0.01f * acc;

    float* og = (side == 0) ? Aog : Bog;
    og[(size_t)q * 128 + j]      = e;
    og[(size_t)q * 128 + 64 + j] = out;
}

// final stage 1: grid 128, block 256; block b: t-rows [16b, 16b+16), LDS-tiled,
// partial[b][i][j] = sum_t Aog[t][i]*Bog[t][j]
__global__ __launch_bounds__(256) void final1_kernel(
    const float* __restrict__ Aog, const float* __restrict__ Bog, float* __restrict__ part)
{
    const int b = blockIdx.x;
    const int t = threadIdx.x;
    __shared__ float As[16][128];
    __shared__ float Bs[16][128];
    {
        float* Asf = &As[0][0];
        float* Bsf = &Bs[0][0];
        const float* Ab = Aog + (size_t)b * 16 * 128;
        const float* Bb = Bog + (size_t)b * 16 * 128;
        #pragma unroll
        for (int qq = 0; qq < 2; ++qq) {
            const int off = qq * 1024 + t * 4;
            *reinterpret_cast<float4*>(Asf + off) = *reinterpret_cast<const float4*>(Ab + off);
            *reinterpret_cast<float4*>(Bsf + off) = *reinterpret_cast<const float4*>(Bb + off);
        }
    }
    __syncthreads();

    const int i0 = (t >> 4) * 8, j0 = (t & 15) * 8;
    float acc[8][8] = {};
    #pragma unroll
    for (int k = 0; k < 16; ++k) {
        float av[8], bv[8];
        *reinterpret_cast<f32x4*>(&av[0]) = *reinterpret_cast<const f32x4*>(&As[k][i0]);
        *reinterpret_cast<f32x4*>(&av[4]) = *reinterpret_cast<const f32x4*>(&As[k][i0 + 4]);
        *reinterpret_cast<f32x4*>(&bv[0]) = *reinterpret_cast<const f32x4*>(&Bs[k][j0]);
        *reinterpret_cast<f32x4*>(&bv[4]) = *reinterpret_cast<const f32x4*>(&Bs[k][j0 + 4]);
        #pragma unroll
        for (int ii = 0; ii < 8; ++ii)
            #pragma unroll
            for (int jj = 0; jj < 8; ++jj)
                acc[ii][jj] += av[ii] * bv[jj];
    }
    float* P = part + (size_t)b * 128 * 128;
    #pragma unroll
    for (int ii = 0; ii < 8; ++ii) {
        *reinterpret_cast<float4*>(P + (i0 + ii) * 128 + j0)     = *reinterpret_cast<float4*>(&acc[ii][0]);
        *reinterpret_cast<float4*>(P + (i0 + ii) * 128 + j0 + 4) = *reinterpret_cast<float4*>(&acc[ii][4]);
    }
}

// final stage 2: grid 128, block 128: out[i][j] = sum_b partial[b][i][j]
__global__ __launch_bounds__(128) void final2_kernel(const float* __restrict__ part,
                                                     float* __restrict__ out)
{
    const int i = blockIdx.x, j = threadIdx.x;
    float s = 0.f;
    #pragma unroll 8
    for (int b = 0; b < 128; ++b) s += part[(size_t)b * 128 * 128 + i * 128 + j];
    out[i * 128 + j] = s;
}

extern "C" void kernel_launch(void* const* d_in, const int* in_sizes, int n_in,
                              void* d_out, int out_size, void* d_ws, size_t ws_size,
                              hipStream_t stream)
{
    (void)in_sizes; (void)n_in; (void)out_size; (void)ws_size;
    const float* user_emb = (const float*)d_in[0];
    const float* item_emb = (const float*)d_in[1];
    const float* uaW = (const float*)d_in[2];
    const float* uab = (const float*)d_in[3];
    const float* uW1 = (const float*)d_in[4];
    const float* uW2 = (const float*)d_in[5];
    const float* iaW = (const float*)d_in[6];
    const float* iab = (const float*)d_in[7];
    const float* iW1 = (const float*)d_in[8];
    const float* iW2 = (const float*)d_in[9];
    const int* user_id = (const int*)d_in[10];
    const int* item_id = (const int*)d_in[11];
    // d_in[12], d_in[13]: arange identity gathers -- no-ops.

    char* ws = (char*)d_ws;
    size_t off = 0;
    auto alloc = [&](size_t bytes) -> void* {
        void* p = ws + off;
        off = (off + bytes + 255) & ~(size_t)255;
        return p;
    };
    unsigned char* Khid8 = (unsigned char*)alloc((size_t)2 * NP * DIM);
    unsigned char* Vpan8 = (unsigned char*)alloc((size_t)2 * (NP / 32) * 2048);
    float* csum  = (float*)alloc((size_t)2 * NTIL * 64 * 4);
    float* csum2 = (float*)alloc((size_t)2 * 64 * 64 * 4);
    float* Sbuf  = (float*)alloc((size_t)2 * 64 * 4);
    float* WT    = (float*)alloc((size_t)4 * 4096 * 4);
    unsigned short* Opart = (unsigned short*)alloc((size_t)2 * BQ * NCH * 64 * 2);
    float* lpart = (float*)alloc((size_t)2 * BQ * NCH * 4);
    float* Aog   = (float*)alloc((size_t)BQ * 128 * 4);
    float* Bog   = (float*)alloc((size_t)BQ * 128 * 4);
    float* Fpart = (float*)alloc((size_t)128 * 128 * 128 * 4);

    prep_kernel<<<dim3(NTIL, 2), 256, 0, stream>>>(user_emb, item_emb, uaW, uab, iaW, iab,
                                                   Khid8, Vpan8, csum);
    sreduceA_kernel<<<dim3(64, 2), 64, 0, stream>>>(csum, csum2);
    sreduceB_kernel<<<2, 64, 0, stream>>>(csum2, Sbuf);
    wtrans_kernel<<<4, 256, 0, stream>>>(uW1, uW2, iW1, iW2, WT);
    flash_kernel<<<dim3(NCH, BQ / 256, 2), 512, 0, stream>>>(user_emb, item_emb, user_id, item_id,
                                                             Khid8, Vpan8, Opart, lpart);
    combine_kernel<<<2 * BQ / 4, 256, 0, stream>>>(user_emb, item_emb, user_id, item_id,
                                                   WT, Opart, lpart, Sbuf, Aog, Bog);
    final1_kernel<<<128, 256, 0, stream>>>(Aog, Bog, Fpart);
    final2_kernel<<<128, 128, 0, stream>>>(Fpart, (float*)d_out);
}

// Round 15
// 128.812 us; speedup vs baseline: 1.1549x; 1.0358x over previous
//
#include <hip/hip_runtime.h>

// ANCF recommender on MI355X.
// prep (MFMA hidden -> Khid fp8; keys^T -> Vpan fp8 n-panels; colsum partials)
//  -> sreduceA/B (S = colsum, 2-stage tree) ; wtrans (W1/W2 -> W^T, once)
//  -> flash (R12 structure: MX-fp8 mfma_scale 32x32x64, 64-n phases, 2x8KB LDS,
//            1 DMA/wave/phase one phase ahead, raw s_barrier, 8-wave blocks.
//            REGISTER DIET this round: lacc 8->2 f32x2 accumulators, Q pack
//            fused per-float4 (no qf[8] prologue peak). Goal: arch VGPR <= 53
//            so unified (arch + 32 AGPR acc) <= 85 -> 24 waves/CU -> 3 blocks
//            resident. NCH=48 -> grid 768 = 3.0 blocks/CU exactly.)
//  -> combine (4-wave blocks, one q per wave: contiguous Opart row,
//              shfl-allreduce lsum (lane<NCH guard), transposed-W epilogue)
//  -> final1/2 (128x128 = og_user^T @ og_item, 128-block k-split)
// Workspace required: ~75 MB.

typedef __bf16 bf16x8 __attribute__((ext_vector_type(8)));
typedef float f32x2 __attribute__((ext_vector_type(2)));
typedef float f32x4 __attribute__((ext_vector_type(4)));
typedef float f32x16 __attribute__((ext_vector_type(16)));
typedef unsigned int u32x4 __attribute__((ext_vector_type(4)));
typedef int i32x4 __attribute__((ext_vector_type(4)));
typedef int i32x8 __attribute__((ext_vector_type(8)));

static constexpr int NKEYS  = 100000;
static constexpr int NP     = 101376;          // 48 chunks * 2112 rows (2112 = 33*64)
static constexpr int DIM    = 64;
static constexpr int BQ     = 2048;
static constexpr int NCH    = 48;              // grid 48*8*2 = 768 = 3 blocks/CU
static constexpr int CHROWS = NP / NCH;        // 2112
static constexpr int NPH    = CHROWS / 64;     // 33 phases of 64 n
static constexpr int NTIL   = NP / 64;         // 1584
static constexpr float PADCNT = float(NP - NKEYS);   // 1376 pads, each adds fexp2(0) to l
static constexpr float LOG2E  = 1.44269504088896340736f;

#define DEVINL __device__ __forceinline__

DEVINL unsigned int cvtpk(float lo, float hi) {
    unsigned int r;
    asm("v_cvt_pk_bf16_f32 %0, %1, %2" : "=v"(r) : "v"(lo), "v"(hi));
    return r;
}
DEVINL unsigned short bfr(float f) {           // single f32 -> bf16 (RNE)
    return (unsigned short)(cvtpk(f, f) & 0xffffu);
}
DEVINL float bf2f(unsigned short u) {
    unsigned int w = (unsigned int)u << 16;
    return __builtin_bit_cast(float, w);
}
DEVINL void permswap(unsigned int& a, unsigned int& b) {
    asm("v_permlane32_swap_b32 %0, %1" : "+v"(a), "+v"(b));
}
DEVINL bf16x8 pack_frag(unsigned int w0, unsigned int w1, unsigned int w2, unsigned int w3) {
    u32x4 t; t[0] = w0; t[1] = w1; t[2] = w2; t[3] = w3;
    return __builtin_bit_cast(bf16x8, t);
}
DEVINL bf16x8 frag8_f32(const float* p) {      // 8 consecutive f32 -> bf16x8 frag
    f32x4 a = *reinterpret_cast<const f32x4*>(p);
    f32x4 b = *reinterpret_cast<const f32x4*>(p + 4);
    return pack_frag(cvtpk(a[0], a[1]), cvtpk(a[2], a[3]),
                     cvtpk(b[0], b[1]), cvtpk(b[2], b[3]));
}
// fp8 e4m3 helpers
DEVINL unsigned int fp8x4(float a, float b, float c, float d) {
    int r = __builtin_amdgcn_cvt_pk_fp8_f32(a, b, 0, false);   // bytes 0,1
    r = __builtin_amdgcn_cvt_pk_fp8_f32(c, d, r, true);        // bytes 2,3
    return (unsigned int)r;
}
DEVINL unsigned char fp8b(float f) {
    return (unsigned char)(__builtin_amdgcn_cvt_pk_fp8_f32(f, f, 0, false) & 0xFF);
}
DEVINL i32x8 cat8(i32x4 a, i32x4 b) {
    return __builtin_shufflevector(a, b, 0, 1, 2, 3, 4, 5, 6, 7);
}
// fp8 e4m3 MFMA, K=64, scales = 1.0 (e8m0 = 127 in every byte)
DEVINL f32x16 mfma8(i32x8 a, i32x8 b, f32x16 c) {
    return __builtin_amdgcn_mfma_scale_f32_32x32x64_f8f6f4(
        a, b, c, 0 /*cbsz: fp8*/, 0 /*blgp: fp8*/,
        0, 0x7F7F7F7F, 0, 0x7F7F7F7F);
}
// Schraudolph fast 2^x (fma + cvt; +-3% rel err, sub-dominant vs fp8's 6%).
// x=0 (pad rows) yields the same deterministic constant in flash and combine.
DEVINL float fexp2(float x) {
    float f = __builtin_fmaf(x, 8388608.0f, 1065713994.0f);
    int i = (int)f;
    return __builtin_bit_cast(float, i);
}
// packed f32 add (v_pk_add_f32): 2 adds in one instruction
DEVINL f32x2 pkadd(f32x2 a, f32x2 b) {
    f32x2 r;
    asm("v_pk_add_f32 %0, %1, %2" : "=v"(r) : "v"(a), "v"(b));
    return r;
}

// ---------------------------------------------------------------------------
// prep: per 64-row tile: hidden = relu(K @ aW^T + b) via 32x32x16 bf16 MFMA
//       -> Khid fp8 [n][64]; K^T -> Vpan fp8 (panels: Vpan[n/32][64 d][32 nn],
//       each panel 2KB contiguous); column-sum partials (f32, exact).
//       Pad rows (n >= NKEYS) exact zeros.
// grid (NTIL, 2), block 256
// ---------------------------------------------------------------------------
__global__ __launch_bounds__(256) void prep_kernel(
    const float* __restrict__ user_emb, const float* __restrict__ item_emb,
    const float* __restrict__ uaW, const float* __restrict__ uab,
    const float* __restrict__ iaW, const float* __restrict__ iab,
    unsigned char* __restrict__ Khid, unsigned char* __restrict__ Vpan,
    float* __restrict__ csum)
{
    const int side = blockIdx.y;
    const int tile = blockIdx.x;
    const float* keys = (side == 0) ? item_emb : user_emb;
    const float* aW   = (side == 0) ? uaW : iaW;
    const float* ab   = (side == 0) ? uab : iab;
    unsigned char* Kh  = Khid + (size_t)side * NP * DIM;
    unsigned char* Vps = Vpan + (size_t)side * (NP / 32) * 2048;

    __shared__ float Kf[64][68];
    __shared__ float Wf[64][68];
    __shared__ float bl[64];

    const int t  = threadIdx.x;
    const int r  = t >> 2;
    const int c0 = (t & 3) * 16;

    {   // stage aW rows (f32)
        const float4* src = reinterpret_cast<const float4*>(aW + r * 64 + c0);
        float4* dst = reinterpret_cast<float4*>(&Wf[r][c0]);
        #pragma unroll
        for (int q = 0; q < 4; ++q) dst[q] = src[q];
        if (t < 64) bl[t] = ab[t];
    }
    {   // stage keys tile (zero pads)
        const int n = tile * 64 + r;
        float4* dst = reinterpret_cast<float4*>(&Kf[r][c0]);
        if (n < NKEYS) {
            const float4* src = reinterpret_cast<const float4*>(keys + (size_t)n * 64 + c0);
            #pragma unroll
            for (int q = 0; q < 4; ++q) dst[q] = src[q];
        } else {
            const float4 z = make_float4(0.f, 0.f, 0.f, 0.f);
            #pragma unroll
            for (int q = 0; q < 4; ++q) dst[q] = z;
        }
    }
    __syncthreads();

    {   // hidden 32x32 tile per wave via bf16 MFMA
        const int wv = t >> 6, lane = t & 63;
        const int c = lane & 31, hi = lane >> 5;
        const int n0 = (wv & 1) * 32, j0 = (wv >> 1) * 32;
        f32x16 acc{};
        #pragma unroll
        for (int ks = 0; ks < 4; ++ks) {
            bf16x8 af = frag8_f32(&Kf[n0 + c][ks * 16 + hi * 8]);
            bf16x8 bf_ = frag8_f32(&Wf[j0 + c][ks * 16 + hi * 8]);
            acc = __builtin_amdgcn_mfma_f32_32x32x16_bf16(af, bf_, acc, 0, 0, 0);
        }
        const float bj = bl[j0 + c];
        #pragma unroll
        for (int rr = 0; rr < 16; ++rr) {
            const int n  = n0 + (rr & 3) + 8 * (rr >> 2) + 4 * hi;
            const int gn = tile * 64 + n;
            float h = fmaxf(acc[rr] + bj, 0.f);
            if (gn >= NKEYS) h = 0.f;
            Kh[(size_t)gn * 64 + j0 + c] = fp8b(h);
        }
    }
    {   // Vpan fp8: thread: d = r, nn-cols c0..c0+15 within this 64-tile
        unsigned int pw[4];
        #pragma unroll
        for (int j = 0; j < 4; ++j)
            pw[j] = fp8x4(Kf[c0 + 4 * j][r],     Kf[c0 + 4 * j + 1][r],
                          Kf[c0 + 4 * j + 2][r], Kf[c0 + 4 * j + 3][r]);
        unsigned char* dst = Vps + ((size_t)(2 * tile + (c0 >> 5))) * 2048 + r * 32 + (c0 & 31);
        *reinterpret_cast<uint4*>(dst) = make_uint4(pw[0], pw[1], pw[2], pw[3]);
    }
    if (t < 64) {   // column partial sums (f32, exact keys)
        float s = 0.f;
        #pragma unroll 8
        for (int rr = 0; rr < 64; ++rr) s += Kf[rr][t];
        csum[((size_t)side * NTIL + tile) * 64 + t] = s;
    }
}

// grid (64, 2), block 64
__global__ __launch_bounds__(64) void sreduceA_kernel(const float* __restrict__ csum,
                                                      float* __restrict__ csum2)
{
    const int j = blockIdx.x, side = blockIdx.y, d = threadIdx.x;
    float s = 0.f;
    for (int idx = j; idx < NTIL; idx += 64)
        s += csum[((size_t)side * NTIL + idx) * 64 + d];
    csum2[((size_t)side * 64 + j) * 64 + d] = s;
}

// grid (2), block 64
__global__ __launch_bounds__(64) void sreduceB_kernel(const float* __restrict__ csum2,
                                                      float* __restrict__ Sbuf)
{
    const int side = blockIdx.x, d = threadIdx.x;
    float s = 0.f;
    #pragma unroll 8
    for (int j = 0; j < 64; ++j) s += csum2[((size_t)side * 64 + j) * 64 + d];
    Sbuf[side * 64 + d] = s;
}

// grid 4, block 256: WT[m][dd][j] = W_m[j][dd]  (m: uW1,uW2,iW1,iW2)
__global__ __launch_bounds__(256) void wtrans_kernel(
    const float* __restrict__ uW1, const float* __restrict__ uW2,
    const float* __restrict__ iW1, const float* __restrict__ iW2,
    float* __restrict__ WT)
{
    const float* W = (blockIdx.x == 0) ? uW1 : (blockIdx.x == 1) ? uW2
                   : (blockIdx.x == 2) ? iW1 : iW2;
    float* T = WT + (size_t)blockIdx.x * 4096;
    const int t = threadIdx.x;
    const int j = t >> 2;
    const int dd0 = (t & 3) * 16;
    #pragma unroll
    for (int k = 0; k < 16; ++k)
        T[(dd0 + k) * 64 + j] = W[j * 64 + dd0 + k];
}

// ---------------------------------------------------------------------------
// flash (MX-fp8): block = 8 waves (512 thr), each wave a 32-query tile; block
//   covers 256 q over one n-chunk of 2112 keys, 33 phases of 64 n.
// Per phase per wave: 2 QK mfma_scale_32x32x64 (K=64 = full d), 32 fexp2,
//   16 pk_add into 2 accumulators, 16 cvt_pk_fp8 + 4 permlane32_swap,
//   2 PV mfma_scale (K=64 = full phase-n), 8 ds_read_b128, 1 DMA issue.
// LDS per buffer (8KB, bytes): K: st*2048 + qh*1024 + hi*512 + c*16
//   (K[st*32+c][d=32hi+16qh+0..15]); V: 4096 + dblk*2048 + qh*1024 + hi*512 +
//   c*16 (V[n=32hi+16qh+0..15][d=32dblk+c]).
// A/B lane (hi,c): row/col = c, k = 32hi + byte j. C/D: col = lane&31,
//   row = (rr&3)+8(rr>>2)+4hi (verified, shape-determined).
// Staging: wave w: dest = buf + w*1024 + lane*16; src K (w<4: st=w>>1, qh=w&1):
//   st*2048 + qh*16 + c*64 + hi*32; src V (w>=4: dblk=(w-4)>>1):
//   dblk*1024 + qh*16 + hi*2048 + c*32. Advance 4096 B/phase. Double-buffered,
//   DMA one full phase ahead; pre-barrier vmcnt(0) waits phase-old loads only.
// Outputs q-major: Opart[side][q][ch][d], lpart[side][q][ch].
// Register diet: arch-VGPR target <= 53 (unified <= 85 -> 24 waves/CU ->
//   3 blocks resident). grid (NCH, 8, 2) = 768 = 3.0 blocks/CU exactly.
// ---------------------------------------------------------------------------
__global__ __launch_bounds__(512) void flash_kernel(
    const float* __restrict__ user_emb, const float* __restrict__ item_emb,
    const int* __restrict__ user_id, const int* __restrict__ item_id,
    const unsigned char* __restrict__ Khid, const unsigned char* __restrict__ Vpan,
    unsigned short* __restrict__ Opart, float* __restrict__ lpart)
{
    const int side  = blockIdx.z;
    const int chunk = blockIdx.x;
    const int qblk  = blockIdx.y;
    const int wave  = threadIdx.x >> 6;
    const int lane  = threadIdx.x & 63;
    const int c  = lane & 31;
    const int hi = lane >> 5;

    __shared__ __align__(16) unsigned char KV[2][8192];   // 2 x 8KB

    const float* emb = (side == 0) ? user_emb : item_emb;
    const int* ids   = (side == 0) ? user_id  : item_id;
    const unsigned char* Kh = Khid + ((size_t)side * NP + (size_t)chunk * CHROWS) * 64;
    const unsigned char* Vb = Vpan + ((size_t)side * (NP / 32) + (size_t)chunk * (CHROWS / 32)) * 2048;

    // ---- staging setup: wave w stages LDS bytes [w*1024, w*1024+1024) per phase
    const unsigned char* gsrc;
    if (wave < 4) {
        const int st = wave >> 1, qh = wave & 1;
        gsrc = Kh + st * 2048 + qh * 16 + c * 64 + hi * 32;
    } else {
        const int dblk = (wave - 4) >> 1, qh = wave & 1;
        gsrc = Vb + dblk * 1024 + qh * 16 + hi * 2048 + c * 32;
    }

    const unsigned char* gnext = gsrc;      // source cursor for next ISSUE
    int ibuf = 0;                           // LDS buffer for next ISSUE
    auto ISSUE = [&]() {
        __builtin_amdgcn_global_load_lds(
            (const __attribute__((address_space(1))) unsigned int*)gnext,
            (__attribute__((address_space(3))) unsigned int*)&KV[ibuf][wave * 1024],
            16, 0, 0);
        gnext += 4096;
        ibuf ^= 1;
    };

    ISSUE();            // phase 0 -> buf 0 (in flight during Q gather/pack)

    // ---- Q gather + fp8 pack, fused per float4 (low prologue register peak)
    const int qtile = qblk * 256 + wave * 32;
    const int id = ids[qtile + c];
    const float* qrow = emb + (size_t)id * 64 + hi * 32;
    i32x8 bq;
    #pragma unroll
    for (int w = 0; w < 8; ++w) {
        float4 f = *reinterpret_cast<const float4*>(qrow + w * 4);
        bq[w] = (int)fp8x4(f.x * LOG2E, f.y * LOG2E, f.z * LOG2E, f.w * LOG2E);
    }

    f32x16 o0{}, o1{};
    f32x2 lacc0{}, lacc1{};

    asm volatile("s_waitcnt vmcnt(0)" ::: "memory");   // phase-0 DMA done
    __builtin_amdgcn_s_barrier();

    for (int p = 0; p < NPH; ++p) {
        if (p + 1 < NPH) ISSUE();

        const unsigned char* Bp = &KV[p & 1][0];
        const int fo = hi * 512 + c * 16;

        // K A-frags (2 st), 2 x b128 each
        i32x8 ak0 = cat8(*reinterpret_cast<const i32x4*>(Bp + fo),
                         *reinterpret_cast<const i32x4*>(Bp + 1024 + fo));
        i32x8 ak1 = cat8(*reinterpret_cast<const i32x4*>(Bp + 2048 + fo),
                         *reinterpret_cast<const i32x4*>(Bp + 3072 + fo));

        __builtin_amdgcn_s_setprio(1);
        f32x16 z{};
        f32x16 s0 = mfma8(ak0, bq, z);     // st0: n = 0..31
        f32x16 s1 = mfma8(ak1, bq, z);     // st1: n = 32..63
        __builtin_amdgcn_s_setprio(0);

        // V B-frags (2 dblk)
        i32x8 bv0 = cat8(*reinterpret_cast<const i32x4*>(Bp + 4096 + fo),
                         *reinterpret_cast<const i32x4*>(Bp + 5120 + fo));
        i32x8 bv1 = cat8(*reinterpret_cast<const i32x4*>(Bp + 6144 + fo),
                         *reinterpret_cast<const i32x4*>(Bp + 7168 + fo));

        // P = fexp2(S)
        #pragma unroll
        for (int rr = 0; rr < 16; ++rr) s0[rr] = fexp2(s0[rr]);
        #pragma unroll
        for (int rr = 0; rr < 16; ++rr) s1[rr] = fexp2(s1[rr]);

        // l accumulate via packed f32 adds into 2 accumulators (static refs)
        #pragma unroll
        for (int g = 0; g < 8; ++g) {
            f32x2 a; a[0] = s0[2 * g]; a[1] = s0[2 * g + 1];
            f32x2 b; b[0] = s1[2 * g]; b[1] = s1[2 * g + 1];
            if (g & 1) lacc1 = pkadd(lacc1, pkadd(a, b));
            else       lacc0 = pkadd(lacc0, pkadd(a, b));
        }

        // P fp8 A-frag via cvt_pk_fp8 + permlane32_swap
        unsigned int p0[4], p1[4];
        #pragma unroll
        for (int g = 0; g < 4; ++g) {
            p0[g] = fp8x4(s0[4 * g], s0[4 * g + 1], s0[4 * g + 2], s0[4 * g + 3]);
            p1[g] = fp8x4(s1[4 * g], s1[4 * g + 1], s1[4 * g + 2], s1[4 * g + 3]);
            permswap(p0[g], p1[g]);
        }
        i32x8 pa;
        pa[0] = (int)p0[0]; pa[1] = (int)p1[0];
        pa[2] = (int)p0[1]; pa[3] = (int)p1[1];
        pa[4] = (int)p0[2]; pa[5] = (int)p1[2];
        pa[6] = (int)p0[3]; pa[7] = (int)p1[3];

        __builtin_amdgcn_s_setprio(1);
        o0 = mfma8(pa, bv0, o0);           // d = 0..31
        o1 = mfma8(pa, bv1, o1);           // d = 32..63
        __builtin_amdgcn_s_setprio(0);

        if (p + 1 < NPH) {
            asm volatile("s_waitcnt vmcnt(0)" ::: "memory");
            __builtin_amdgcn_s_barrier();
        }
    }

    float ls = (lacc0[0] + lacc0[1]) + (lacc1[0] + lacc1[1]);
    ls += __shfl_xor(ls, 32);   // lane c now holds l[qtile+c] for this chunk

    // q-major outputs
    unsigned short* Op = Opart + (((size_t)(side * BQ + qtile)) * NCH + chunk) * 64;
    #pragma unroll
    for (int rr = 0; rr < 16; ++rr) {
        const int q = (rr & 3) + 8 * (rr >> 2) + 4 * hi;
        Op[(size_t)q * NCH * 64 + c]      = bfr(o0[rr]);
        Op[(size_t)q * NCH * 64 + 32 + c] = bfr(o1[rr]);
    }
    if (hi == 0)
        lpart[((size_t)(side * BQ + qtile + c)) * NCH + chunk] = ls;
}

// ---------------------------------------------------------------------------
// combine: 4-wave blocks, one q per wave (lane = output dim j).
//   num[j] = sum_ch Opart[side][q][ch][j]   (contiguous row, coalesced)
//   lsum   = shfl-allreduce of lpart[side][q][ch] (lane<NCH guard)
//   q2 = e + num/(lsum - PADCNT*fexp2(0));
//   out = leaky_relu(sum_dd a1[dd]*W1T[dd][j] + a2[dd]*W2T[dd][j])  (coalesced)
// grid (2*BQ/4) = 1024, block 256
// ---------------------------------------------------------------------------
__global__ __launch_bounds__(256) void combine_kernel(
    const float* __restrict__ user_emb, const float* __restrict__ item_emb,
    const int* __restrict__ user_id, const int* __restrict__ item_id,
    const float* __restrict__ WT,
    const unsigned short* __restrict__ Opart, const float* __restrict__ lpart,
    const float* __restrict__ Sbuf,
    float* __restrict__ Aog, float* __restrict__ Bog)
{
    const int bid  = blockIdx.x;
    const int side = bid >> 9;
    const int wave = threadIdx.x >> 6;
    const int lane = threadIdx.x & 63;
    const int q    = ((bid & 511) << 2) + wave;
    const int j    = lane;

    const unsigned short* Ob = Opart + ((size_t)(side * BQ + q)) * (NCH * 64) + j;
    float num = 0.f;
    #pragma unroll 8
    for (int ch = 0; ch < NCH; ++ch)
        num += bf2f(Ob[ch * 64]);

    float lv = (lane < NCH) ? lpart[((size_t)(side * BQ + q)) * NCH + lane] : 0.f;
    #pragma unroll
    for (int m = 32; m >= 1; m >>= 1) lv += __shfl_xor(lv, m);
    const float lsum = lv - PADCNT * fexp2(0.0f);

    const int id = ((side == 0) ? user_id : item_id)[q];
    const float* emb = (side == 0) ? user_emb : item_emb;
    const float e  = emb[(size_t)id * 64 + j];
    const float q2 = e + num / lsum;
    const float Sd = Sbuf[side * 64 + j];

    __shared__ float a1s[4][64], a2s[4][64];
    a1s[wave][j] = q2 + Sd;
    a2s[wave][j] = q2 * Sd;
    // intra-wave LDS write->read: lockstep, compiler inserts lgkmcnt

    const float* W1T = WT + (size_t)side * 8192;        // [dd][j]
    const float* W2T = W1T + 4096;
    float acc = 0.f;
    #pragma unroll 8
    for (int dd = 0; dd < 64; ++dd)
        acc += a1s[wave][dd] * W1T[dd * 64 + j] + a2s[wave][dd] * W2T[dd * 64 + j];
    const float out = (acc >= 0.f) ? acc : 0.01f * acc;

    float* og = (side == 0) ? Aog : Bog;
    og[(size_t)q * 128 + j]      = e;
    og[(size_t)q * 128 + 64 + j] = out;
}

// final stage 1: grid 128, block 256; block b: t-rows [16b, 16b+16), LDS-tiled,
// partial[b][i][j] = sum_t Aog[t][i]*Bog[t][j]
__global__ __launch_bounds__(256) void final1_kernel(
    const float* __restrict__ Aog, const float* __restrict__ Bog, float* __restrict__ part)
{
    const int b = blockIdx.x;
    const int t = threadIdx.x;
    __shared__ float As[16][128];
    __shared__ float Bs[16][128];
    {
        float* Asf = &As[0][0];
        float* Bsf = &Bs[0][0];
        const float* Ab = Aog + (size_t)b * 16 * 128;
        const float* Bb = Bog + (size_t)b * 16 * 128;
        #pragma unroll
        for (int qq = 0; qq < 2; ++qq) {
            const int off = qq * 1024 + t * 4;
            *reinterpret_cast<float4*>(Asf + off) = *reinterpret_cast<const float4*>(Ab + off);
            *reinterpret_cast<float4*>(Bsf + off) = *reinterpret_cast<const float4*>(Bb + off);
        }
    }
    __syncthreads();

    const int i0 = (t >> 4) * 8, j0 = (t & 15) * 8;
    float acc[8][8] = {};
    #pragma unroll
    for (int k = 0; k < 16; ++k) {
        float av[8], bv[8];
        *reinterpret_cast<f32x4*>(&av[0]) = *reinterpret_cast<const f32x4*>(&As[k][i0]);
        *reinterpret_cast<f32x4*>(&av[4]) = *reinterpret_cast<const f32x4*>(&As[k][i0 + 4]);
        *reinterpret_cast<f32x4*>(&bv[0]) = *reinterpret_cast<const f32x4*>(&Bs[k][j0]);
        *reinterpret_cast<f32x4*>(&bv[4]) = *reinterpret_cast<const f32x4*>(&Bs[k][j0 + 4]);
        #pragma unroll
        for (int ii = 0; ii < 8; ++ii)
            #pragma unroll
            for (int jj = 0; jj < 8; ++jj)
                acc[ii][jj] += av[ii] * bv[jj];
    }
    float* P = part + (size_t)b * 128 * 128;
    #pragma unroll
    for (int ii = 0; ii < 8; ++ii) {
        *reinterpret_cast<float4*>(P + (i0 + ii) * 128 + j0)     = *reinterpret_cast<float4*>(&acc[ii][0]);
        *reinterpret_cast<float4*>(P + (i0 + ii) * 128 + j0 + 4) = *reinterpret_cast<float4*>(&acc[ii][4]);
    }
}

// final stage 2: grid 128, block 128: out[i][j] = sum_b partial[b][i][j]
__global__ __launch_bounds__(128) void final2_kernel(const float* __restrict__ part,
                                                     float* __restrict__ out)
{
    const int i = blockIdx.x, j = threadIdx.x;
    float s = 0.f;
    #pragma unroll 8
    for (int b = 0; b < 128; ++b) s += part[(size_t)b * 128 * 128 + i * 128 + j];
    out[i * 128 + j] = s;
}

extern "C" void kernel_launch(void* const* d_in, const int* in_sizes, int n_in,
                              void* d_out, int out_size, void* d_ws, size_t ws_size,
                              hipStream_t stream)
{
    (void)in_sizes; (void)n_in; (void)out_size; (void)ws_size;
    const float* user_emb = (const float*)d_in[0];
    const float* item_emb = (const float*)d_in[1];
    const float* uaW = (const float*)d_in[2];
    const float* uab = (const float*)d_in[3];
    const float* uW1 = (const float*)d_in[4];
    const float* uW2 = (const float*)d_in[5];
    const float* iaW = (const float*)d_in[6];
    const float* iab = (const float*)d_in[7];
    const float* iW1 = (const float*)d_in[8];
    const float* iW2 = (const float*)d_in[9];
    const int* user_id = (const int*)d_in[10];
    const int* item_id = (const int*)d_in[11];
    // d_in[12], d_in[13]: arange identity gathers -- no-ops.

    char* ws = (char*)d_ws;
    size_t off = 0;
    auto alloc = [&](size_t bytes) -> void* {
        void* p = ws + off;
        off = (off + bytes + 255) & ~(size_t)255;
        return p;
    };
    unsigned char* Khid8 = (unsigned char*)alloc((size_t)2 * NP * DIM);
    unsigned char* Vpan8 = (unsigned char*)alloc((size_t)2 * (NP / 32) * 2048);
    float* csum  = (float*)alloc((size_t)2 * NTIL * 64 * 4);
    float* csum2 = (float*)alloc((size_t)2 * 64 * 64 * 4);
    float* Sbuf  = (float*)alloc((size_t)2 * 64 * 4);
    float* WT    = (float*)alloc((size_t)4 * 4096 * 4);
    unsigned short* Opart = (unsigned short*)alloc((size_t)2 * BQ * NCH * 64 * 2);
    float* lpart = (float*)alloc((size_t)2 * BQ * NCH * 4);
    float* Aog   = (float*)alloc((size_t)BQ * 128 * 4);
    float* Bog   = (float*)alloc((size_t)BQ * 128 * 4);
    float* Fpart = (float*)alloc((size_t)128 * 128 * 128 * 4);

    prep_kernel<<<dim3(NTIL, 2), 256, 0, stream>>>(user_emb, item_emb, uaW, uab, iaW, iab,
                                                   Khid8, Vpan8, csum);
    sreduceA_kernel<<<dim3(64, 2), 64, 0, stream>>>(csum, csum2);
    sreduceB_kernel<<<2, 64, 0, stream>>>(csum2, Sbuf);
    wtrans_kernel<<<4, 256, 0, stream>>>(uW1, uW2, iW1, iW2, WT);
    flash_kernel<<<dim3(NCH, BQ / 256, 2), 512, 0, stream>>>(user_emb, item_emb, user_id, item_id,
                                                             Khid8, Vpan8, Opart, lpart);
    combine_kernel<<<2 * BQ / 4, 256, 0, stream>>>(user_emb, item_emb, user_id, item_id,
                                                   WT, Opart, lpart, Sbuf, Aog, Bog);
    final1_kernel<<<128, 256, 0, stream>>>(Aog, Bog, Fpart);
    final2_kernel<<<128, 128, 0, stream>>>(Fpart, (float*)d_out);
}

// Round 16
// 126.764 us; speedup vs baseline: 1.1735x; 1.0162x over previous
//
#include <hip/hip_runtime.h>

// ANCF recommender on MI355X.
// prep (MFMA hidden -> Khid fp8; keys^T -> Vpan fp8 n-panels; colsum partials)
//  -> sreduceA/B (S = colsum, 2-stage tree) ; wtrans (W1/W2 -> W^T, once)
//  -> flash (MX-fp8 mfma_scale 32x32x64, 64-n phases, 8-wave blocks, NCH=48.
//            THIS ROUND: (1) zero-copy MFMA operand loads (ds_read_b128 pairs
//            land directly in the 8-reg tuple via union halves; pa assembled
//            in place) -- kills ~40 v_mov/phase of operand-assembly overhead;
//            (2) triple-buffered LDS (3x8KB) with depth-2 DMA prefetch and
//            counted vmcnt(1) (never 0 mid-loop) -- ~2 phases of HBM lead.)
//  -> combine (4-wave blocks, one q per wave, coalesced Opart + W^T epilogue)
//  -> final1/2 (128x128 = og_user^T @ og_item, 128-block k-split)
// Workspace required: ~75 MB.

typedef __bf16 bf16x8 __attribute__((ext_vector_type(8)));
typedef float f32x2 __attribute__((ext_vector_type(2)));
typedef float f32x4 __attribute__((ext_vector_type(4)));
typedef float f32x16 __attribute__((ext_vector_type(16)));
typedef unsigned int u32x4 __attribute__((ext_vector_type(4)));
typedef int i32x4 __attribute__((ext_vector_type(4)));
typedef int i32x8 __attribute__((ext_vector_type(8)));

static constexpr int NKEYS  = 100000;
static constexpr int NP     = 101376;          // 48 chunks * 2112 rows (2112 = 33*64)
static constexpr int DIM    = 64;
static constexpr int BQ     = 2048;
static constexpr int NCH    = 48;
static constexpr int CHROWS = NP / NCH;        // 2112
static constexpr int NPH    = CHROWS / 64;     // 33 phases of 64 n
static constexpr int NTIL   = NP / 64;         // 1584
static constexpr float PADCNT = float(NP - NKEYS);   // 1376 pads, each adds fexp2(0) to l
static constexpr float LOG2E  = 1.44269504088896340736f;

#define DEVINL __device__ __forceinline__

DEVINL unsigned int cvtpk(float lo, float hi) {
    unsigned int r;
    asm("v_cvt_pk_bf16_f32 %0, %1, %2" : "=v"(r) : "v"(lo), "v"(hi));
    return r;
}
DEVINL unsigned short bfr(float f) {           // single f32 -> bf16 (RNE)
    return (unsigned short)(cvtpk(f, f) & 0xffffu);
}
DEVINL float bf2f(unsigned short u) {
    unsigned int w = (unsigned int)u << 16;
    return __builtin_bit_cast(float, w);
}
DEVINL void permswap(unsigned int& a, unsigned int& b) {
    asm("v_permlane32_swap_b32 %0, %1" : "+v"(a), "+v"(b));
}
DEVINL bf16x8 pack_frag(unsigned int w0, unsigned int w1, unsigned int w2, unsigned int w3) {
    u32x4 t; t[0] = w0; t[1] = w1; t[2] = w2; t[3] = w3;
    return __builtin_bit_cast(bf16x8, t);
}
DEVINL bf16x8 frag8_f32(const float* p) {      // 8 consecutive f32 -> bf16x8 frag
    f32x4 a = *reinterpret_cast<const f32x4*>(p);
    f32x4 b = *reinterpret_cast<const f32x4*>(p + 4);
    return pack_frag(cvtpk(a[0], a[1]), cvtpk(a[2], a[3]),
                     cvtpk(b[0], b[1]), cvtpk(b[2], b[3]));
}
// fp8 e4m3 helpers
DEVINL unsigned int fp8x4(float a, float b, float c, float d) {
    int r = __builtin_amdgcn_cvt_pk_fp8_f32(a, b, 0, false);   // bytes 0,1
    r = __builtin_amdgcn_cvt_pk_fp8_f32(c, d, r, true);        // bytes 2,3
    return (unsigned int)r;
}
DEVINL unsigned char fp8b(float f) {
    return (unsigned char)(__builtin_amdgcn_cvt_pk_fp8_f32(f, f, 0, false) & 0xFF);
}
// zero-copy 8-reg tuple load: two ds_read_b128 into the halves of one i32x8
DEVINL i32x8 ld8(const unsigned char* lo, const unsigned char* hi) {
    union { i32x8 v; i32x4 h[2]; } u;
    u.h[0] = *reinterpret_cast<const i32x4*>(lo);
    u.h[1] = *reinterpret_cast<const i32x4*>(hi);
    return u.v;
}
// fp8 e4m3 MFMA, K=64, scales = 1.0 (e8m0 = 127 in every byte)
DEVINL f32x16 mfma8(i32x8 a, i32x8 b, f32x16 c) {
    return __builtin_amdgcn_mfma_scale_f32_32x32x64_f8f6f4(
        a, b, c, 0 /*cbsz: fp8*/, 0 /*blgp: fp8*/,
        0, 0x7F7F7F7F, 0, 0x7F7F7F7F);
}
// Schraudolph fast 2^x (fma + cvt; +-3% rel err, sub-dominant vs fp8's 6%).
// x=0 (pad rows) yields the same deterministic constant in flash and combine.
DEVINL float fexp2(float x) {
    float f = __builtin_fmaf(x, 8388608.0f, 1065713994.0f);
    int i = (int)f;
    return __builtin_bit_cast(float, i);
}
// packed f32 add (v_pk_add_f32): 2 adds in one instruction
DEVINL f32x2 pkadd(f32x2 a, f32x2 b) {
    f32x2 r;
    asm("v_pk_add_f32 %0, %1, %2" : "=v"(r) : "v"(a), "v"(b));
    return r;
}

// ---------------------------------------------------------------------------
// prep: per 64-row tile: hidden = relu(K @ aW^T + b) via 32x32x16 bf16 MFMA
//       -> Khid fp8 [n][64]; K^T -> Vpan fp8 (panels: Vpan[n/32][64 d][32 nn],
//       each panel 2KB contiguous); column-sum partials (f32, exact).
//       Pad rows (n >= NKEYS) exact zeros.
// grid (NTIL, 2), block 256
// ---------------------------------------------------------------------------
__global__ __launch_bounds__(256) void prep_kernel(
    const float* __restrict__ user_emb, const float* __restrict__ item_emb,
    const float* __restrict__ uaW, const float* __restrict__ uab,
    const float* __restrict__ iaW, const float* __restrict__ iab,
    unsigned char* __restrict__ Khid, unsigned char* __restrict__ Vpan,
    float* __restrict__ csum)
{
    const int side = blockIdx.y;
    const int tile = blockIdx.x;
    const float* keys = (side == 0) ? item_emb : user_emb;
    const float* aW   = (side == 0) ? uaW : iaW;
    const float* ab   = (side == 0) ? uab : iab;
    unsigned char* Kh  = Khid + (size_t)side * NP * DIM;
    unsigned char* Vps = Vpan + (size_t)side * (NP / 32) * 2048;

    __shared__ float Kf[64][68];
    __shared__ float Wf[64][68];
    __shared__ float bl[64];

    const int t  = threadIdx.x;
    const int r  = t >> 2;
    const int c0 = (t & 3) * 16;

    {   // stage aW rows (f32)
        const float4* src = reinterpret_cast<const float4*>(aW + r * 64 + c0);
        float4* dst = reinterpret_cast<float4*>(&Wf[r][c0]);
        #pragma unroll
        for (int q = 0; q < 4; ++q) dst[q] = src[q];
        if (t < 64) bl[t] = ab[t];
    }
    {   // stage keys tile (zero pads)
        const int n = tile * 64 + r;
        float4* dst = reinterpret_cast<float4*>(&Kf[r][c0]);
        if (n < NKEYS) {
            const float4* src = reinterpret_cast<const float4*>(keys + (size_t)n * 64 + c0);
            #pragma unroll
            for (int q = 0; q < 4; ++q) dst[q] = src[q];
        } else {
            const float4 z = make_float4(0.f, 0.f, 0.f, 0.f);
            #pragma unroll
            for (int q = 0; q < 4; ++q) dst[q] = z;
        }
    }
    __syncthreads();

    {   // hidden 32x32 tile per wave via bf16 MFMA
        const int wv = t >> 6, lane = t & 63;
        const int c = lane & 31, hi = lane >> 5;
        const int n0 = (wv & 1) * 32, j0 = (wv >> 1) * 32;
        f32x16 acc{};
        #pragma unroll
        for (int ks = 0; ks < 4; ++ks) {
            bf16x8 af = frag8_f32(&Kf[n0 + c][ks * 16 + hi * 8]);
            bf16x8 bf_ = frag8_f32(&Wf[j0 + c][ks * 16 + hi * 8]);
            acc = __builtin_amdgcn_mfma_f32_32x32x16_bf16(af, bf_, acc, 0, 0, 0);
        }
        const float bj = bl[j0 + c];
        #pragma unroll
        for (int rr = 0; rr < 16; ++rr) {
            const int n  = n0 + (rr & 3) + 8 * (rr >> 2) + 4 * hi;
            const int gn = tile * 64 + n;
            float h = fmaxf(acc[rr] + bj, 0.f);
            if (gn >= NKEYS) h = 0.f;
            Kh[(size_t)gn * 64 + j0 + c] = fp8b(h);
        }
    }
    {   // Vpan fp8: thread: d = r, nn-cols c0..c0+15 within this 64-tile
        unsigned int pw[4];
        #pragma unroll
        for (int j = 0; j < 4; ++j)
            pw[j] = fp8x4(Kf[c0 + 4 * j][r],     Kf[c0 + 4 * j + 1][r],
                          Kf[c0 + 4 * j + 2][r], Kf[c0 + 4 * j + 3][r]);
        unsigned char* dst = Vps + ((size_t)(2 * tile + (c0 >> 5))) * 2048 + r * 32 + (c0 & 31);
        *reinterpret_cast<uint4*>(dst) = make_uint4(pw[0], pw[1], pw[2], pw[3]);
    }
    if (t < 64) {   // column partial sums (f32, exact keys)
        float s = 0.f;
        #pragma unroll 8
        for (int rr = 0; rr < 64; ++rr) s += Kf[rr][t];
        csum[((size_t)side * NTIL + tile) * 64 + t] = s;
    }
}

// grid (64, 2), block 64
__global__ __launch_bounds__(64) void sreduceA_kernel(const float* __restrict__ csum,
                                                      float* __restrict__ csum2)
{
    const int j = blockIdx.x, side = blockIdx.y, d = threadIdx.x;
    float s = 0.f;
    for (int idx = j; idx < NTIL; idx += 64)
        s += csum[((size_t)side * NTIL + idx) * 64 + d];
    csum2[((size_t)side * 64 + j) * 64 + d] = s;
}

// grid (2), block 64
__global__ __launch_bounds__(64) void sreduceB_kernel(const float* __restrict__ csum2,
                                                      float* __restrict__ Sbuf)
{
    const int side = blockIdx.x, d = threadIdx.x;
    float s = 0.f;
    #pragma unroll 8
    for (int j = 0; j < 64; ++j) s += csum2[((size_t)side * 64 + j) * 64 + d];
    Sbuf[side * 64 + d] = s;
}

// grid 4, block 256: WT[m][dd][j] = W_m[j][dd]  (m: uW1,uW2,iW1,iW2)
__global__ __launch_bounds__(256) void wtrans_kernel(
    const float* __restrict__ uW1, const float* __restrict__ uW2,
    const float* __restrict__ iW1, const float* __restrict__ iW2,
    float* __restrict__ WT)
{
    const float* W = (blockIdx.x == 0) ? uW1 : (blockIdx.x == 1) ? uW2
                   : (blockIdx.x == 2) ? iW1 : iW2;
    float* T = WT + (size_t)blockIdx.x * 4096;
    const int t = threadIdx.x;
    const int j = t >> 2;
    const int dd0 = (t & 3) * 16;
    #pragma unroll
    for (int k = 0; k < 16; ++k)
        T[(dd0 + k) * 64 + j] = W[j * 64 + dd0 + k];
}

// ---------------------------------------------------------------------------
// flash (MX-fp8): block = 8 waves (512 thr), each wave a 32-query tile; block
//   covers 256 q over one n-chunk of 2112 keys, 33 phases of 64 n.
// Per phase per wave: 2 QK mfma_scale_32x32x64 (K=64 = full d), 32 fexp2,
//   16 pk_add into 2 accumulators, 16 cvt_pk_fp8 + 4 permlane32_swap (written
//   directly into the pa tuple via union -- zero assembly moves), 2 PV
//   mfma_scale (K=64 = full phase-n), 8 ds_read_b128 (zero-copy into tuples),
//   1 DMA issue (depth-2 prefetch).
// LDS: TRIPLE-buffered 3 x 8KB. Per buffer: K: st*2048 + qh*1024 + hi*512 +
//   c*16 (K[st*32+c][d=32hi+16qh+0..15]); V: 4096 + dblk*2048 + qh*1024 +
//   hi*512 + c*16 (V[n=32hi+16qh+0..15][d=32dblk+c]).
// A/B lane (hi,c): row/col = c, k = 32hi + byte j. C/D: col = lane&31,
//   row = (rr&3)+8(rr>>2)+4hi (verified, shape-determined).
// Staging: wave w: dest = buf + w*1024 + lane*16; src K (w<4: st=w>>1, qh=w&1):
//   st*2048 + qh*16 + c*64 + hi*32; src V (w>=4: dblk=(w-4)>>1):
//   dblk*1024 + qh*16 + hi*2048 + c*32. Advance 4096 B/phase.
//   DMA issued 2 phases ahead; pre-barrier vmcnt(1) (vmcnt(0) only at tail).
// Outputs q-major: Opart[side][q][ch][d], lpart[side][q][ch].
// grid (NCH, 8, 2) = 768 blocks.
// ---------------------------------------------------------------------------
__global__ __launch_bounds__(512) void flash_kernel(
    const float* __restrict__ user_emb, const float* __restrict__ item_emb,
    const int* __restrict__ user_id, const int* __restrict__ item_id,
    const unsigned char* __restrict__ Khid, const unsigned char* __restrict__ Vpan,
    unsigned short* __restrict__ Opart, float* __restrict__ lpart)
{
    const int side  = blockIdx.z;
    const int chunk = blockIdx.x;
    const int qblk  = blockIdx.y;
    const int wave  = threadIdx.x >> 6;
    const int lane  = threadIdx.x & 63;
    const int c  = lane & 31;
    const int hi = lane >> 5;

    __shared__ __align__(16) unsigned char KV[3][8192];   // 3 x 8KB

    const float* emb = (side == 0) ? user_emb : item_emb;
    const int* ids   = (side == 0) ? user_id  : item_id;
    const unsigned char* Kh = Khid + ((size_t)side * NP + (size_t)chunk * CHROWS) * 64;
    const unsigned char* Vb = Vpan + ((size_t)side * (NP / 32) + (size_t)chunk * (CHROWS / 32)) * 2048;

    // ---- staging setup: wave w stages LDS bytes [w*1024, w*1024+1024) per phase
    const unsigned char* gsrc;
    if (wave < 4) {
        const int st = wave >> 1, qh = wave & 1;
        gsrc = Kh + st * 2048 + qh * 16 + c * 64 + hi * 32;
    } else {
        const int dblk = (wave - 4) >> 1, qh = wave & 1;
        gsrc = Vb + dblk * 1024 + qh * 16 + hi * 2048 + c * 32;
    }

    const unsigned char* gnext = gsrc;      // source cursor for next ISSUE
    int ibuf = 0;                           // LDS buffer for next ISSUE
    auto ISSUE = [&]() {
        __builtin_amdgcn_global_load_lds(
            (const __attribute__((address_space(1))) unsigned int*)gnext,
            (__attribute__((address_space(3))) unsigned int*)&KV[ibuf][wave * 1024],
            16, 0, 0);
        gnext += 4096;
        ibuf = (ibuf == 2) ? 0 : ibuf + 1;
    };

    ISSUE();            // phase 0 -> buf 0
    ISSUE();            // phase 1 -> buf 1 (both in flight during Q pack)

    // ---- Q gather + fp8 pack, fused per float4 (low prologue register peak)
    const int qtile = qblk * 256 + wave * 32;
    const int id = ids[qtile + c];
    const float* qrow = emb + (size_t)id * 64 + hi * 32;
    i32x8 bq;
    #pragma unroll
    for (int w = 0; w < 8; ++w) {
        float4 f = *reinterpret_cast<const float4*>(qrow + w * 4);
        bq[w] = (int)fp8x4(f.x * LOG2E, f.y * LOG2E, f.z * LOG2E, f.w * LOG2E);
    }

    f32x16 o0{}, o1{};
    f32x2 lacc0{}, lacc1{};

    asm volatile("s_waitcnt vmcnt(1)" ::: "memory");   // phase-0 DMA done
    __builtin_amdgcn_s_barrier();

    int cbuf = 0;                           // buffer being consumed
    for (int p = 0; p < NPH; ++p) {
        if (p + 2 < NPH) ISSUE();

        const unsigned char* Bp = &KV[cbuf][0];
        cbuf = (cbuf == 2) ? 0 : cbuf + 1;
        const int fo = hi * 512 + c * 16;

        // K A-frags (2 st): zero-copy tuple loads
        i32x8 ak0 = ld8(Bp + fo,        Bp + 1024 + fo);
        i32x8 ak1 = ld8(Bp + 2048 + fo, Bp + 3072 + fo);

        __builtin_amdgcn_s_setprio(1);
        f32x16 z{};
        f32x16 s0 = mfma8(ak0, bq, z);     // st0: n = 0..31
        f32x16 s1 = mfma8(ak1, bq, z);     // st1: n = 32..63
        __builtin_amdgcn_s_setprio(0);

        // V B-frags (2 dblk): zero-copy tuple loads
        i32x8 bv0 = ld8(Bp + 4096 + fo, Bp + 5120 + fo);
        i32x8 bv1 = ld8(Bp + 6144 + fo, Bp + 7168 + fo);

        // P = fexp2(S)
        #pragma unroll
        for (int rr = 0; rr < 16; ++rr) s0[rr] = fexp2(s0[rr]);
        #pragma unroll
        for (int rr = 0; rr < 16; ++rr) s1[rr] = fexp2(s1[rr]);

        // l accumulate via packed f32 adds into 2 accumulators
        #pragma unroll
        for (int g = 0; g < 8; ++g) {
            f32x2 a; a[0] = s0[2 * g]; a[1] = s0[2 * g + 1];
            f32x2 b; b[0] = s1[2 * g]; b[1] = s1[2 * g + 1];
            if (g & 1) lacc1 = pkadd(lacc1, pkadd(a, b));
            else       lacc0 = pkadd(lacc0, pkadd(a, b));
        }

        // P fp8 A-frag: cvt_pk_fp8 + permlane32_swap written in place (union)
        union { i32x8 v; unsigned int w[8]; } pu;
        #pragma unroll
        for (int g = 0; g < 4; ++g) {
            pu.w[2 * g]     = fp8x4(s0[4 * g], s0[4 * g + 1], s0[4 * g + 2], s0[4 * g + 3]);
            pu.w[2 * g + 1] = fp8x4(s1[4 * g], s1[4 * g + 1], s1[4 * g + 2], s1[4 * g + 3]);
            permswap(pu.w[2 * g], pu.w[2 * g + 1]);
        }

        __builtin_amdgcn_s_setprio(1);
        o0 = mfma8(pu.v, bv0, o0);         // d = 0..31
        o1 = mfma8(pu.v, bv1, o1);         // d = 32..63
        __builtin_amdgcn_s_setprio(0);

        if (p + 1 < NPH) {
            // next phase's DMA was issued >= 2 phases ago; newest may be in flight
            if (p + 2 < NPH) asm volatile("s_waitcnt vmcnt(1)" ::: "memory");
            else             asm volatile("s_waitcnt vmcnt(0)" ::: "memory");
            __builtin_amdgcn_s_barrier();
        }
    }

    float ls = (lacc0[0] + lacc0[1]) + (lacc1[0] + lacc1[1]);
    ls += __shfl_xor(ls, 32);   // lane c now holds l[qtile+c] for this chunk

    // q-major outputs
    unsigned short* Op = Opart + (((size_t)(side * BQ + qtile)) * NCH + chunk) * 64;
    #pragma unroll
    for (int rr = 0; rr < 16; ++rr) {
        const int q = (rr & 3) + 8 * (rr >> 2) + 4 * hi;
        Op[(size_t)q * NCH * 64 + c]      = bfr(o0[rr]);
        Op[(size_t)q * NCH * 64 + 32 + c] = bfr(o1[rr]);
    }
    if (hi == 0)
        lpart[((size_t)(side * BQ + qtile + c)) * NCH + chunk] = ls;
}

// ---------------------------------------------------------------------------
// combine: 4-wave blocks, one q per wave (lane = output dim j).
//   num[j] = sum_ch Opart[side][q][ch][j]   (contiguous row, coalesced)
//   lsum   = shfl-allreduce of lpart[side][q][ch] (lane<NCH guard)
//   q2 = e + num/(lsum - PADCNT*fexp2(0));
//   out = leaky_relu(sum_dd a1[dd]*W1T[dd][j] + a2[dd]*W2T[dd][j])  (coalesced)
// grid (2*BQ/4) = 1024, block 256
// ---------------------------------------------------------------------------
__global__ __launch_bounds__(256) void combine_kernel(
    const float* __restrict__ user_emb, const float* __restrict__ item_emb,
    const int* __restrict__ user_id, const int* __restrict__ item_id,
    const float* __restrict__ WT,
    const unsigned short* __restrict__ Opart, const float* __restrict__ lpart,
    const float* __restrict__ Sbuf,
    float* __restrict__ Aog, float* __restrict__ Bog)
{
    const int bid  = blockIdx.x;
    const int side = bid >> 9;
    const int wave = threadIdx.x >> 6;
    const int lane = threadIdx.x & 63;
    const int q    = ((bid & 511) << 2) + wave;
    const int j    = lane;

    const unsigned short* Ob = Opart + ((size_t)(side * BQ + q)) * (NCH * 64) + j;
    float num = 0.f;
    #pragma unroll 8
    for (int ch = 0; ch < NCH; ++ch)
        num += bf2f(Ob[ch * 64]);

    float lv = (lane < NCH) ? lpart[((size_t)(side * BQ + q)) * NCH + lane] : 0.f;
    #pragma unroll
    for (int m = 32; m >= 1; m >>= 1) lv += __shfl_xor(lv, m);
    const float lsum = lv - PADCNT * fexp2(0.0f);

    const int id = ((side == 0) ? user_id : item_id)[q];
    const float* emb = (side == 0) ? user_emb : item_emb;
    const float e  = emb[(size_t)id * 64 + j];
    const float q2 = e + num / lsum;
    const float Sd = Sbuf[side * 64 + j];

    __shared__ float a1s[4][64], a2s[4][64];
    a1s[wave][j] = q2 + Sd;
    a2s[wave][j] = q2 * Sd;
    // intra-wave LDS write->read: lockstep, compiler inserts lgkmcnt

    const float* W1T = WT + (size_t)side * 8192;        // [dd][j]
    const float* W2T = W1T + 4096;
    float acc = 0.f;
    #pragma unroll 8
    for (int dd = 0; dd < 64; ++dd)
        acc += a1s[wave][dd] * W1T[dd * 64 + j] + a2s[wave][dd] * W2T[dd * 64 + j];
    const float out = (acc >= 0.f) ? acc : 0.01f * acc;

    float* og = (side == 0) ? Aog : Bog;
    og[(size_t)q * 128 + j]      = e;
    og[(size_t)q * 128 + 64 + j] = out;
}

// final stage 1: grid 128, block 256; block b: t-rows [16b, 16b+16), LDS-tiled,
// partial[b][i][j] = sum_t Aog[t][i]*Bog[t][j]
__global__ __launch_bounds__(256) void final1_kernel(
    const float* __restrict__ Aog, const float* __restrict__ Bog, float* __restrict__ part)
{
    const int b = blockIdx.x;
    const int t = threadIdx.x;
    __shared__ float As[16][128];
    __shared__ float Bs[16][128];
    {
        float* Asf = &As[0][0];
        float* Bsf = &Bs[0][0];
        const float* Ab = Aog + (size_t)b * 16 * 128;
        const float* Bb = Bog + (size_t)b * 16 * 128;
        #pragma unroll
        for (int qq = 0; qq < 2; ++qq) {
            const int off = qq * 1024 + t * 4;
            *reinterpret_cast<float4*>(Asf + off) = *reinterpret_cast<const float4*>(Ab + off);
            *reinterpret_cast<float4*>(Bsf + off) = *reinterpret_cast<const float4*>(Bb + off);
        }
    }
    __syncthreads();

    const int i0 = (t >> 4) * 8, j0 = (t & 15) * 8;
    float acc[8][8] = {};
    #pragma unroll
    for (int k = 0; k < 16; ++k) {
        float av[8], bv[8];
        *reinterpret_cast<f32x4*>(&av[0]) = *reinterpret_cast<const f32x4*>(&As[k][i0]);
        *reinterpret_cast<f32x4*>(&av[4]) = *reinterpret_cast<const f32x4*>(&As[k][i0 + 4]);
        *reinterpret_cast<f32x4*>(&bv[0]) = *reinterpret_cast<const f32x4*>(&Bs[k][j0]);
        *reinterpret_cast<f32x4*>(&bv[4]) = *reinterpret_cast<const f32x4*>(&Bs[k][j0 + 4]);
        #pragma unroll
        for (int ii = 0; ii < 8; ++ii)
            #pragma unroll
            for (int jj = 0; jj < 8; ++jj)
                acc[ii][jj] += av[ii] * bv[jj];
    }
    float* P = part + (size_t)b * 128 * 128;
    #pragma unroll
    for (int ii = 0; ii < 8; ++ii) {
        *reinterpret_cast<float4*>(P + (i0 + ii) * 128 + j0)     = *reinterpret_cast<float4*>(&acc[ii][0]);
        *reinterpret_cast<float4*>(P + (i0 + ii) * 128 + j0 + 4) = *reinterpret_cast<float4*>(&acc[ii][4]);
    }
}

// final stage 2: grid 128, block 128: out[i][j] = sum_b partial[b][i][j]
__global__ __launch_bounds__(128) void final2_kernel(const float* __restrict__ part,
                                                     float* __restrict__ out)
{
    const int i = blockIdx.x, j = threadIdx.x;
    float s = 0.f;
    #pragma unroll 8
    for (int b = 0; b < 128; ++b) s += part[(size_t)b * 128 * 128 + i * 128 + j];
    out[i * 128 + j] = s;
}

extern "C" void kernel_launch(void* const* d_in, const int* in_sizes, int n_in,
                              void* d_out, int out_size, void* d_ws, size_t ws_size,
                              hipStream_t stream)
{
    (void)in_sizes; (void)n_in; (void)out_size; (void)ws_size;
    const float* user_emb = (const float*)d_in[0];
    const float* item_emb = (const float*)d_in[1];
    const float* uaW = (const float*)d_in[2];
    const float* uab = (const float*)d_in[3];
    const float* uW1 = (const float*)d_in[4];
    const float* uW2 = (const float*)d_in[5];
    const float* iaW = (const float*)d_in[6];
    const float* iab = (const float*)d_in[7];
    const float* iW1 = (const float*)d_in[8];
    const float* iW2 = (const float*)d_in[9];
    const int* user_id = (const int*)d_in[10];
    const int* item_id = (const int*)d_in[11];
    // d_in[12], d_in[13]: arange identity gathers -- no-ops.

    char* ws = (char*)d_ws;
    size_t off = 0;
    auto alloc = [&](size_t bytes) -> void* {
        void* p = ws + off;
        off = (off + bytes + 255) & ~(size_t)255;
        return p;
    };
    unsigned char* Khid8 = (unsigned char*)alloc((size_t)2 * NP * DIM);
    unsigned char* Vpan8 = (unsigned char*)alloc((size_t)2 * (NP / 32) * 2048);
    float* csum  = (float*)alloc((size_t)2 * NTIL * 64 * 4);
    float* csum2 = (float*)alloc((size_t)2 * 64 * 64 * 4);
    float* Sbuf  = (float*)alloc((size_t)2 * 64 * 4);
    float* WT    = (float*)alloc((size_t)4 * 4096 * 4);
    unsigned short* Opart = (unsigned short*)alloc((size_t)2 * BQ * NCH * 64 * 2);
    float* lpart = (float*)alloc((size_t)2 * BQ * NCH * 4);
    float* Aog   = (float*)alloc((size_t)BQ * 128 * 4);
    float* Bog   = (float*)alloc((size_t)BQ * 128 * 4);
    float* Fpart = (float*)alloc((size_t)128 * 128 * 128 * 4);

    prep_kernel<<<dim3(NTIL, 2), 256, 0, stream>>>(user_emb, item_emb, uaW, uab, iaW, iab,
                                                   Khid8, Vpan8, csum);
    sreduceA_kernel<<<dim3(64, 2), 64, 0, stream>>>(csum, csum2);
    sreduceB_kernel<<<2, 64, 0, stream>>>(csum2, Sbuf);
    wtrans_kernel<<<4, 256, 0, stream>>>(uW1, uW2, iW1, iW2, WT);
    flash_kernel<<<dim3(NCH, BQ / 256, 2), 512, 0, stream>>>(user_emb, item_emb, user_id, item_id,
                                                             Khid8, Vpan8, Opart, lpart);
    combine_kernel<<<2 * BQ / 4, 256, 0, stream>>>(user_emb, item_emb, user_id, item_id,
                                                   WT, Opart, lpart, Sbuf, Aog, Bog);
    final1_kernel<<<128, 256, 0, stream>>>(Aog, Bog, Fpart);
    final2_kernel<<<128, 128, 0, stream>>>(Fpart, (float*)d_out);
}